// Round 1
// baseline (5640.845 us; speedup 1.0000x reference)
//
#include <hip/hip_runtime.h>
#include <hip/hip_bf16.h>

// ---------------------------------------------------------------------------
// Transformer decoder (eval mode), fp32 end-to-end.
// B=2, ST=SS=1024, D=512, H=8, DK=64, L=4, DFF=2048, V=32000.
// d_out = [out (2*1024*32000)] ++ [self_attns (4*2*8*1024*1024)]
//       ++ [cross_attns (4*2*8*1024*1024)]  (all fp32)
// Workspace usage: 9,437,184 floats = 36 MB.
// ---------------------------------------------------------------------------

#define D_MODEL 512
#define NHEAD   8
#define DKH     64
#define SEQ     1024
#define NLAYER  4
#define DFF_    2048
#define VOCAB   32000
#define BATCH   2
#define MROWS   (BATCH*SEQ)   // 2048

// ---------------- embedding + positional encoding ----------------
__global__ __launch_bounds__(256) void embed_pe_kernel(
    const int* __restrict__ tokens, const float* __restrict__ emb,
    float* __restrict__ x)
{
    long idx = (long)blockIdx.x * 256 + threadIdx.x;   // over B*ST*D = 1,048,576
    int  d   = (int)(idx & (D_MODEL - 1));
    long row = idx >> 9;                 // b*SEQ + s
    int  s   = (int)(row & (SEQ - 1));
    int  tok = tokens[row];
    // pe[s, 2i]   = sin(s * exp(2i * -ln(10000)/512))
    // pe[s, 2i+1] = cos(s * exp(2i * -ln(10000)/512))
    float twoi = (float)((d >> 1) << 1);
    float div  = expf(twoi * (-9.210340371976184f / 512.0f));
    float arg  = (float)s * div;
    float pe   = (d & 1) ? cosf(arg) : sinf(arg);
    x[idx] = emb[(long)tok * D_MODEL + d] * 22.62741699796952f + pe; // sqrt(512)
}

// ---------------- tiled fp32 GEMM:  C = act(A[M,K] @ W[K,N] + bias) ----------
// blockIdx.z selects weight/bias/output slab via strides (QKV batching).
#define BM 128
#define BN 64
#define BKT 16

template<int ACT>  // 0 = none, 1 = relu
__global__ __launch_bounds__(256) void gemm_bias_kernel(
    const float* __restrict__ A, const float* __restrict__ W,
    const float* __restrict__ bias, float* __restrict__ C,
    int M, int N, int K, long wStride, long bStride, long cStride)
{
    long z = blockIdx.z;
    W    += z * wStride;
    bias += z * bStride;
    C    += z * cStride;

    const int m0 = blockIdx.y * BM;
    const int n0 = blockIdx.x * BN;

    // As transposed [k][m] with +4 pad (keeps rows 16B-aligned, 2-way banks max)
    __shared__ float As[BKT][BM + 4];
    __shared__ float Bs[BKT][BN];

    const int t  = threadIdx.x;
    const int tx = t & 15;        // n-direction (4 cols)
    const int ty = t >> 4;        // m-direction (8 rows)

    float acc[8][4];
#pragma unroll
    for (int i = 0; i < 8; ++i)
#pragma unroll
        for (int j = 0; j < 4; ++j) acc[i][j] = 0.f;

    for (int k0 = 0; k0 < K; k0 += BKT) {
        // A tile 128x16 -> As[c][r]
#pragma unroll
        for (int i = 0; i < 8; ++i) {
            int e = t + i * 256;
            int r = e >> 4, c = e & 15;
            As[c][r] = A[(long)(m0 + r) * K + k0 + c];
        }
        // W tile 16x64 -> Bs[r][c]  (coalesced)
#pragma unroll
        for (int i = 0; i < 4; ++i) {
            int e = t + i * 256;
            int r = e >> 6, c = e & 63;
            Bs[r][c] = W[(long)(k0 + r) * N + n0 + c];
        }
        __syncthreads();
#pragma unroll
        for (int kk = 0; kk < BKT; ++kk) {
            const float4 a0 = *(const float4*)(&As[kk][ty * 8]);
            const float4 a1 = *(const float4*)(&As[kk][ty * 8 + 4]);
            const float4 bv = *(const float4*)(&Bs[kk][tx * 4]);
            float ar[8] = {a0.x,a0.y,a0.z,a0.w,a1.x,a1.y,a1.z,a1.w};
            float br[4] = {bv.x,bv.y,bv.z,bv.w};
#pragma unroll
            for (int i = 0; i < 8; ++i)
#pragma unroll
                for (int j = 0; j < 4; ++j)
                    acc[i][j] = fmaf(ar[i], br[j], acc[i][j]);
        }
        __syncthreads();
    }

    const float4 bv = *(const float4*)(&bias[n0 + tx * 4]);
#pragma unroll
    for (int i = 0; i < 8; ++i) {
        long row = m0 + ty * 8 + i;
        float4 v;
        v.x = acc[i][0] + bv.x;
        v.y = acc[i][1] + bv.y;
        v.z = acc[i][2] + bv.z;
        v.w = acc[i][3] + bv.w;
        if (ACT == 1) {
            v.x = fmaxf(v.x, 0.f); v.y = fmaxf(v.y, 0.f);
            v.z = fmaxf(v.z, 0.f); v.w = fmaxf(v.w, 0.f);
        }
        *(float4*)(&C[row * (long)N + n0 + tx * 4]) = v;
    }
}

// ---------------- fused attention: scores -> softmax (written out) -> PV -----
// Grid: (SEQ/8, NHEAD, BATCH). Block 256. QT=8 q-rows per block.
// Q/K/V are [B, S, D] with head h occupying cols h*64..h*64+63.
// attn written to [B,H,Sq,Sk]; O written to [B,Sq,D].
template<bool CAUSAL>
__global__ __launch_bounds__(256) void attention_kernel(
    const float* __restrict__ Qm, const float* __restrict__ Km,
    const float* __restrict__ Vm, float* __restrict__ attn,
    float* __restrict__ Om)
{
    const int Sk = SEQ;
    const int b  = blockIdx.z, h = blockIdx.y;
    const int q0 = blockIdx.x * 8;

    __shared__ float Qs[8][64];
    __shared__ float KT[64][33];      // transposed chunk [d][kk], conflict-free
    __shared__ float P[8][SEQ];       // 32 KB

    const int t = threadIdx.x;

    // load 8 Q rows (512 elems)
#pragma unroll
    for (int i = 0; i < 2; ++i) {
        int e = t + i * 256; int r = e >> 6, d = e & 63;
        Qs[r][d] = Qm[(long)(b * SEQ + q0 + r) * D_MODEL + h * DKH + d];
    }

    const int kk_t = t & 31, r_t = t >> 5;   // 32 k-lanes x 8 rows
    const int qg = q0 + r_t;

    // ---- scores ----
    for (int kc = 0; kc < Sk; kc += 32) {
        // stage K chunk transposed: KT[d][kk]
#pragma unroll
        for (int i = 0; i < 8; ++i) {
            int e = t + i * 256; int kk = e >> 6, d = e & 63;
            KT[d][kk] = Km[(long)(b * Sk + kc + kk) * D_MODEL + h * DKH + d];
        }
        __syncthreads();
        int k = kc + kk_t;
        float s;
        if (CAUSAL && k > qg) {
            s = -1e9f;                       // matches reference mask fill
        } else {
            s = 0.f;
#pragma unroll
            for (int d = 0; d < 64; ++d)
                s = fmaf(Qs[r_t][d], KT[d][kk_t], s);
            s *= 0.125f;                     // 1/sqrt(64)
        }
        P[r_t][k] = s;
        __syncthreads();
    }

    // ---- softmax over each row (32 lanes per row) ----
    float mx = -3.4e38f;
    for (int k = kk_t; k < Sk; k += 32) mx = fmaxf(mx, P[r_t][k]);
#pragma unroll
    for (int m = 16; m; m >>= 1) mx = fmaxf(mx, __shfl_xor(mx, m, 64));
    float sum = 0.f;
    for (int k = kk_t; k < Sk; k += 32) {
        float e = expf(P[r_t][k] - mx);      // exp(-1e9 - mx) == 0 exactly
        P[r_t][k] = e; sum += e;
    }
#pragma unroll
    for (int m = 16; m; m >>= 1) sum += __shfl_xor(sum, m, 64);
    float inv = 1.f / sum;
    float* arow = attn + ((long)((b * NHEAD + h) * SEQ + qg)) * Sk;
    for (int k = kk_t; k < Sk; k += 32) {
        float p = P[r_t][k] * inv;
        P[r_t][k] = p;
        arow[k] = p;                         // coalesced 128B per half-wave
    }
    __syncthreads();

    // ---- PV: O[r][d] = sum_k P[r][k] * V[k][d] ----
    const int d_t = t & 63, rr = t >> 6;     // rr in 0..3, handles rows rr, rr+4
    float acc0 = 0.f, acc1 = 0.f;
    for (int kc = 0; kc < Sk; kc += 32) {
#pragma unroll
        for (int i = 0; i < 8; ++i) {
            int e = t + i * 256; int kk = e >> 6, d = e & 63;
            KT[d][kk] = Vm[(long)(b * Sk + kc + kk) * D_MODEL + h * DKH + d];
        }
        __syncthreads();
#pragma unroll
        for (int kk = 0; kk < 32; ++kk) {
            float v = KT[d_t][kk];
            acc0 = fmaf(P[rr][kc + kk],     v, acc0);
            acc1 = fmaf(P[rr + 4][kc + kk], v, acc1);
        }
        __syncthreads();
    }
    Om[(long)(b * SEQ + q0 + rr)     * D_MODEL + h * DKH + d_t] = acc0;
    Om[(long)(b * SEQ + q0 + rr + 4) * D_MODEL + h * DKH + d_t] = acc1;
}

// ---------------- residual add + LayerNorm (biased var, eps=1e-5) ------------
__global__ __launch_bounds__(256) void add_ln_kernel(
    const float* __restrict__ xin, const float* __restrict__ y,
    const float* __restrict__ g, const float* __restrict__ bb,
    float* __restrict__ xout)
{
    long row = blockIdx.x;
    const float* xr = xin + row * D_MODEL;
    const float* yr = y   + row * D_MODEL;
    float*       xo = xout+ row * D_MODEL;
    int t = threadIdx.x;

    float a0 = xr[t]       + yr[t];
    float a1 = xr[t + 256] + yr[t + 256];

    float s = a0 + a1;
#pragma unroll
    for (int m = 32; m; m >>= 1) s += __shfl_xor(s, m, 64);
    __shared__ float red1[4];
    __shared__ float red2[4];
    int w = t >> 6, lane = t & 63;
    if (lane == 0) red1[w] = s;
    __syncthreads();
    float mean = (red1[0] + red1[1] + red1[2] + red1[3]) * (1.f / 512.f);

    float d0 = a0 - mean, d1 = a1 - mean;
    float q = d0 * d0 + d1 * d1;
#pragma unroll
    for (int m = 32; m; m >>= 1) q += __shfl_xor(q, m, 64);
    if (lane == 0) red2[w] = q;
    __syncthreads();
    float var  = (red2[0] + red2[1] + red2[2] + red2[3]) * (1.f / 512.f);
    float rstd = rsqrtf(var + 1e-5f);

    xo[t]       = d0 * rstd * g[t]       + bb[t];
    xo[t + 256] = d1 * rstd * g[t + 256] + bb[t + 256];
}

// ---------------------------------------------------------------------------
extern "C" void kernel_launch(void* const* d_in, const int* in_sizes, int n_in,
                              void* d_out, int out_size, void* d_ws, size_t ws_size,
                              hipStream_t stream)
{
    const int*   tokens = (const int*)  d_in[0];
    const float* enc    = (const float*)d_in[1];
    // d_in[2] = tgt_mask (causal tril) -- implied by CAUSAL template
    const float* emb    = (const float*)d_in[3];
    const float* Wqkvo  = (const float*)d_in[4];   // [L,2,4,D,D]
    const float* bqkvo  = (const float*)d_in[5];   // [L,2,4,D]
    const float* W1     = (const float*)d_in[6];   // [L,D,DFF]
    const float* b1     = (const float*)d_in[7];
    const float* W2     = (const float*)d_in[8];   // [L,DFF,D]
    const float* b2     = (const float*)d_in[9];
    const float* lng    = (const float*)d_in[10];  // [L,3,D]
    const float* lnb    = (const float*)d_in[11];
    const float* Wout   = (const float*)d_in[12];  // [D,V]
    const float* bout   = (const float*)d_in[13];

    float* out    = (float*)d_out;
    float* selfA  = out + 65536000L;               // [L,B,H,ST,ST]
    float* crossA = selfA + 67108864L;             // [L,B,H,ST,SS]

    // workspace carve (floats): x 1M | qkv 3M | o 1M | t1 4M  = 36 MB
    float* x   = (float*)d_ws;
    float* qkv = x   + 1048576L;
    float* o   = qkv + 3L * 1048576L;
    float* t1  = o   + 1048576L;

    const long PW = 262144L;   // 512*512 per projection matrix
    const long XS = 1048576L;  // 2048*512

    embed_pe_kernel<<<4096, 256, 0, stream>>>(tokens, emb, x);

    for (int l = 0; l < NLAYER; ++l) {
        const float* Wl = Wqkvo + (long)l * 2097152L;   // [2,4,512,512]
        const float* bl = bqkvo + (long)l * 4096L;
        const float* g  = lng + (long)l * 3 * 512;
        const float* bb = lnb + (long)l * 3 * 512;

        // ---- self-attention ----
        gemm_bias_kernel<0><<<dim3(8, 16, 3), 256, 0, stream>>>(
            x, Wl, bl, qkv, MROWS, 512, 512, PW, 512L, XS);            // Q,K,V
        attention_kernel<true><<<dim3(128, 8, 2), 256, 0, stream>>>(
            qkv, qkv + XS, qkv + 2 * XS, selfA + (long)l * 16777216L, o);
        gemm_bias_kernel<0><<<dim3(8, 16, 1), 256, 0, stream>>>(
            o, Wl + 3 * PW, bl + 3 * 512, t1, MROWS, 512, 512, 0, 0, 0); // O proj
        add_ln_kernel<<<MROWS, 256, 0, stream>>>(x, t1, g, bb, x);

        // ---- cross-attention ----
        const float* Wc = Wl + 4 * PW;
        const float* bc = bl + 4 * 512;
        gemm_bias_kernel<0><<<dim3(8, 16, 1), 256, 0, stream>>>(
            x, Wc, bc, qkv, MROWS, 512, 512, 0, 0, 0);                 // Q from x
        gemm_bias_kernel<0><<<dim3(8, 16, 2), 256, 0, stream>>>(
            enc, Wc + PW, bc + 512, qkv + XS, MROWS, 512, 512, PW, 512L, XS); // K,V from enc
        attention_kernel<false><<<dim3(128, 8, 2), 256, 0, stream>>>(
            qkv, qkv + XS, qkv + 2 * XS, crossA + (long)l * 16777216L, o);
        gemm_bias_kernel<0><<<dim3(8, 16, 1), 256, 0, stream>>>(
            o, Wc + 3 * PW, bc + 3 * 512, t1, MROWS, 512, 512, 0, 0, 0);
        add_ln_kernel<<<MROWS, 256, 0, stream>>>(x, t1, g + 512, bb + 512, x);

        // ---- FFN ----
        gemm_bias_kernel<1><<<dim3(32, 16, 1), 256, 0, stream>>>(
            x, W1 + (long)l * 1048576L, b1 + (long)l * 2048, t1,
            MROWS, DFF_, 512, 0, 0, 0);                                // relu
        gemm_bias_kernel<0><<<dim3(8, 16, 1), 256, 0, stream>>>(
            t1, W2 + (long)l * 1048576L, b2 + (long)l * 512, o,
            MROWS, 512, DFF_, 0, 0, 0);
        add_ln_kernel<<<MROWS, 256, 0, stream>>>(x, o, g + 1024, bb + 1024, x);
    }

    // ---- final vocab projection ----
    gemm_bias_kernel<0><<<dim3(500, 16, 1), 256, 0, stream>>>(
        x, Wout, bout, out, MROWS, VOCAB, 512, 0, 0, 0);
}

// Round 2
// 3567.390 us; speedup vs baseline: 1.5812x; 1.5812x over previous
//
#include <hip/hip_runtime.h>
#include <hip/hip_bf16.h>

// ---------------------------------------------------------------------------
// Transformer decoder, fp32 I/O, split-bf16 MFMA GEMMs (hi/lo, 3 products).
// B=2, ST=SS=1024, D=512, H=8, DK=64, L=4, DFF=2048, V=32000.
// ---------------------------------------------------------------------------

#define D_MODEL 512
#define NHEAD   8
#define DKH     64
#define SEQ     1024
#define NLAYER  4
#define DFF_    2048
#define VOCAB   32000
#define BATCH   2
#define MROWS   (BATCH*SEQ)   // 2048

typedef short bf16x8 __attribute__((ext_vector_type(8)));
typedef float f32x4  __attribute__((ext_vector_type(4)));

static __device__ __forceinline__ short f2bf(float f) {
    __hip_bfloat16 h = __float2bfloat16(f);
    return *reinterpret_cast<short*>(&h);
}
static __device__ __forceinline__ float bf2f(short s) {
    __hip_bfloat16 h = *reinterpret_cast<__hip_bfloat16*>(&s);
    return __bfloat162float(h);
}
static __device__ __forceinline__ void gld16(const void* g, void* l) {
    __builtin_amdgcn_global_load_lds(
        (__attribute__((address_space(1))) void*)(void*)g,
        (__attribute__((address_space(3))) void*)l, 16, 0, 0);
}

// ---------------- embedding + positional encoding + hi/lo -------------------
__global__ __launch_bounds__(256) void embed_pe_kernel(
    const int* __restrict__ tokens, const float* __restrict__ emb,
    float* __restrict__ x, short* __restrict__ xh, short* __restrict__ xl)
{
    long idx = (long)blockIdx.x * 256 + threadIdx.x;   // over 1,048,576
    int  d   = (int)(idx & (D_MODEL - 1));
    long row = idx >> 9;
    int  s   = (int)(row & (SEQ - 1));
    int  tok = tokens[row];
    float twoi = (float)((d >> 1) << 1);
    float div  = expf(twoi * (-9.210340371976184f / 512.0f));
    float arg  = (float)s * div;
    float pe   = (d & 1) ? cosf(arg) : sinf(arg);
    float v = emb[(long)tok * D_MODEL + d] * 22.62741699796952f + pe; // sqrt(512)
    x[idx] = v;
    short h = f2bf(v);
    xh[idx] = h;
    xl[idx] = f2bf(v - bf2f(h));
}

// ---------------- fp32 -> bf16 hi/lo (straight layout) ----------------------
__global__ __launch_bounds__(256) void cvt_kernel(
    const float* __restrict__ in, short* __restrict__ h, short* __restrict__ l)
{
    long e = ((long)blockIdx.x * 256 + threadIdx.x) * 4;
    float4 v = *(const float4*)&in[e];
    float f[4] = {v.x, v.y, v.z, v.w};
#pragma unroll
    for (int i = 0; i < 4; ++i) {
        short hh = f2bf(f[i]);
        h[e + i] = hh;
        l[e + i] = f2bf(f[i] - bf2f(hh));
    }
}

// ---------------- weight transpose-convert: W[K,N] -> WT[N,K] hi/lo ---------
// grid: (Ncols/64, K/64, Z)
__global__ __launch_bounds__(256) void wtrans_kernel(
    const float* __restrict__ W, short* __restrict__ Th, short* __restrict__ Tl,
    int K, int ldW, long zW, long zT)
{
    long z = blockIdx.z;
    W  += z * zW;
    Th += z * zT;
    Tl += z * zT;
    const int n0 = blockIdx.x * 64, k0 = blockIdx.y * 64;
    __shared__ float tile[64][65];
    const int t = threadIdx.x;
#pragma unroll
    for (int i = 0; i < 4; ++i) {
        int e = t + i * 256; int kk = e >> 4; int nn = (e & 15) * 4;
        float4 v = *(const float4*)&W[(long)(k0 + kk) * ldW + n0 + nn];
        tile[kk][nn] = v.x; tile[kk][nn + 1] = v.y;
        tile[kk][nn + 2] = v.z; tile[kk][nn + 3] = v.w;
    }
    __syncthreads();
    const int n = t >> 2, ks = (t & 3) * 16;
    short h8[16], l8[16];
#pragma unroll
    for (int j = 0; j < 16; ++j) {
        float f = tile[ks + j][n];
        short h = f2bf(f);
        h8[j] = h;
        l8[j] = f2bf(f - bf2f(h));
    }
    long base = (long)(n0 + n) * K + k0 + ks;
    *(bf16x8*)&Th[base]     = *(bf16x8*)&h8[0];
    *(bf16x8*)&Th[base + 8] = *(bf16x8*)&h8[8];
    *(bf16x8*)&Tl[base]     = *(bf16x8*)&l8[0];
    *(bf16x8*)&Tl[base + 8] = *(bf16x8*)&l8[8];
}

// ---------------- split-bf16 MFMA GEMM --------------------------------------
// C[M,N] = act(Ah+Al)[M,K] @ (Bh+Bl)^T[N,K]  + bias   (3-product split)
// BT x BT tile, 256 threads (4 waves, 2x2), BK=32, 16x16x32 bf16 MFMA.
// MODE 0: write fp32 C.  MODE 2: write bf16 hi/lo Ch/Cl.
template<int BT, int ACT, int MODE>
__global__ __launch_bounds__(256) void gemm_mfma_kernel(
    const short* __restrict__ Ah, const short* __restrict__ Al,
    const short* __restrict__ Bh, const short* __restrict__ Bl,
    const float* __restrict__ bias, float* __restrict__ C,
    short* __restrict__ Ch, short* __restrict__ Cl,
    int K, int ldc, long zB, long zBias, long zC)
{
    constexpr int HM = BT / 2;    // wave tile span
    constexpr int MT = BT / 32;   // 16x16 frags per wave dim (128->4, 64->2)
    const long z = blockIdx.z;
    Bh += z * zB; Bl += z * zB; bias += z * zBias;

    const int n0 = blockIdx.x * BT, m0 = blockIdx.y * BT;
    const int t = threadIdx.x;
    const int w = t >> 6, lane = t & 63;
    const int wm = w >> 1, wn = w & 1;
    const int lr = lane & 15, ks = lane >> 4;

    __shared__ short sAh[BT * 32], sAl[BT * 32], sBh[BT * 32], sBl[BT * 32];

    f32x4 acc[MT][MT];
#pragma unroll
    for (int i = 0; i < MT; ++i)
#pragma unroll
        for (int j = 0; j < MT; ++j) acc[i][j] = (f32x4){0.f, 0.f, 0.f, 0.f};

    const long rowA = (long)m0 * K * 2;   // byte offsets
    const long rowB = (long)n0 * K * 2;

    for (int k0 = 0; k0 < K; k0 += 32) {
#pragma unroll
        for (int i = 0; i < BT / 64; ++i) {
            const int  L = i * 4096 + t * 16;          // byte offset in tile
            const int  r = L >> 6;                     // tile row
            const int  s = L & 63;                     // byte within 64B row
            const long gb = ((long)r * K + k0) * 2 + s;
            gld16((const char*)Ah + rowA + gb, (char*)sAh + L);
            gld16((const char*)Al + rowA + gb, (char*)sAl + L);
            gld16((const char*)Bh + rowB + gb, (char*)sBh + L);
            gld16((const char*)Bl + rowB + gb, (char*)sBl + L);
        }
        __syncthreads();

        bf16x8 ah[MT], al[MT], bh[MT], bl[MT];
#pragma unroll
        for (int mt = 0; mt < MT; ++mt) {
            int row = wm * HM + mt * 16 + lr;
            ah[mt] = *(const bf16x8*)&sAh[row * 32 + ks * 8];
            al[mt] = *(const bf16x8*)&sAl[row * 32 + ks * 8];
            int col = wn * HM + mt * 16 + lr;
            bh[mt] = *(const bf16x8*)&sBh[col * 32 + ks * 8];
            bl[mt] = *(const bf16x8*)&sBl[col * 32 + ks * 8];
        }
#pragma unroll
        for (int mt = 0; mt < MT; ++mt)
#pragma unroll
            for (int nt = 0; nt < MT; ++nt) {
                acc[mt][nt] = __builtin_amdgcn_mfma_f32_16x16x32_bf16(
                    ah[mt], bh[nt], acc[mt][nt], 0, 0, 0);
                acc[mt][nt] = __builtin_amdgcn_mfma_f32_16x16x32_bf16(
                    ah[mt], bl[nt], acc[mt][nt], 0, 0, 0);
                acc[mt][nt] = __builtin_amdgcn_mfma_f32_16x16x32_bf16(
                    al[mt], bh[nt], acc[mt][nt], 0, 0, 0);
            }
        __syncthreads();
    }

    // epilogue: C/D layout col=lane&15, row=(lane>>4)*4+i
    const int rq = lane >> 4, cq = lane & 15;
#pragma unroll
    for (int mt = 0; mt < MT; ++mt)
#pragma unroll
        for (int nt = 0; nt < MT; ++nt) {
            int gr0 = m0 + wm * HM + mt * 16 + rq * 4;
            int gc  = n0 + wn * HM + nt * 16 + cq;
            float bv = bias[gc];
#pragma unroll
            for (int i = 0; i < 4; ++i) {
                float v = acc[mt][nt][i] + bv;
                if (ACT == 1) v = fmaxf(v, 0.f);
                long off = (long)(gr0 + i) * ldc + gc + z * zC;
                if (MODE == 0) {
                    C[off] = v;
                } else {
                    short h = f2bf(v);
                    Ch[off] = h;
                    Cl[off] = f2bf(v - bf2f(h));
                }
            }
        }
}

// ---------------- fused attention (fp32): scores -> softmax -> PV -----------
// Output O written only as bf16 hi/lo (consumed by O-proj MFMA GEMM).
template<bool CAUSAL>
__global__ __launch_bounds__(256) void attention_kernel(
    const float* __restrict__ Qm, const float* __restrict__ Km,
    const float* __restrict__ Vm, float* __restrict__ attn,
    short* __restrict__ Oh, short* __restrict__ Ol)
{
    const int Sk = SEQ;
    const int b  = blockIdx.z, h = blockIdx.y;
    const int q0 = blockIdx.x * 8;

    __shared__ float Qs[8][64];
    __shared__ float KT[64][33];
    __shared__ float P[8][SEQ];

    const int t = threadIdx.x;

#pragma unroll
    for (int i = 0; i < 2; ++i) {
        int e = t + i * 256; int r = e >> 6, d = e & 63;
        Qs[r][d] = Qm[(long)(b * SEQ + q0 + r) * D_MODEL + h * DKH + d];
    }

    const int kk_t = t & 31, r_t = t >> 5;
    const int qg = q0 + r_t;

    for (int kc = 0; kc < Sk; kc += 32) {
#pragma unroll
        for (int i = 0; i < 8; ++i) {
            int e = t + i * 256; int kk = e >> 6, d = e & 63;
            KT[d][kk] = Km[(long)(b * Sk + kc + kk) * D_MODEL + h * DKH + d];
        }
        __syncthreads();
        int k = kc + kk_t;
        float s;
        if (CAUSAL && k > qg) {
            s = -1e9f;
        } else {
            s = 0.f;
#pragma unroll
            for (int d = 0; d < 64; ++d)
                s = fmaf(Qs[r_t][d], KT[d][kk_t], s);
            s *= 0.125f;
        }
        P[r_t][k] = s;
        __syncthreads();
    }

    float mx = -3.4e38f;
    for (int k = kk_t; k < Sk; k += 32) mx = fmaxf(mx, P[r_t][k]);
#pragma unroll
    for (int m = 16; m; m >>= 1) mx = fmaxf(mx, __shfl_xor(mx, m, 64));
    float sum = 0.f;
    for (int k = kk_t; k < Sk; k += 32) {
        float e = expf(P[r_t][k] - mx);
        P[r_t][k] = e; sum += e;
    }
#pragma unroll
    for (int m = 16; m; m >>= 1) sum += __shfl_xor(sum, m, 64);
    float inv = 1.f / sum;
    float* arow = attn + ((long)((b * NHEAD + h) * SEQ + qg)) * Sk;
    for (int k = kk_t; k < Sk; k += 32) {
        float p = P[r_t][k] * inv;
        P[r_t][k] = p;
        arow[k] = p;
    }
    __syncthreads();

    const int d_t = t & 63, rr = t >> 6;
    float acc0 = 0.f, acc1 = 0.f;
    for (int kc = 0; kc < Sk; kc += 32) {
#pragma unroll
        for (int i = 0; i < 8; ++i) {
            int e = t + i * 256; int kk = e >> 6, d = e & 63;
            KT[d][kk] = Vm[(long)(b * Sk + kc + kk) * D_MODEL + h * DKH + d];
        }
        __syncthreads();
#pragma unroll
        for (int kk = 0; kk < 32; ++kk) {
            float v = KT[d_t][kk];
            acc0 = fmaf(P[rr][kc + kk],     v, acc0);
            acc1 = fmaf(P[rr + 4][kc + kk], v, acc1);
        }
        __syncthreads();
    }
    long o0 = (long)(b * SEQ + q0 + rr) * D_MODEL + h * DKH + d_t;
    long o1 = (long)(b * SEQ + q0 + rr + 4) * D_MODEL + h * DKH + d_t;
    short h0 = f2bf(acc0); Oh[o0] = h0; Ol[o0] = f2bf(acc0 - bf2f(h0));
    short h1 = f2bf(acc1); Oh[o1] = h1; Ol[o1] = f2bf(acc1 - bf2f(h1));
}

// ---------------- residual add + LayerNorm + hi/lo --------------------------
__global__ __launch_bounds__(256) void add_ln_kernel(
    const float* __restrict__ xin, const float* __restrict__ y,
    const float* __restrict__ g, const float* __restrict__ bb,
    float* __restrict__ xout, short* __restrict__ xh, short* __restrict__ xl)
{
    long row = blockIdx.x;
    const float* xr = xin + row * D_MODEL;
    const float* yr = y   + row * D_MODEL;
    float*       xo = xout+ row * D_MODEL;
    short*       hh = xh  + row * D_MODEL;
    short*       ll = xl  + row * D_MODEL;
    int t = threadIdx.x;

    float a0 = xr[t]       + yr[t];
    float a1 = xr[t + 256] + yr[t + 256];

    float s = a0 + a1;
#pragma unroll
    for (int m = 32; m; m >>= 1) s += __shfl_xor(s, m, 64);
    __shared__ float red1[4];
    __shared__ float red2[4];
    int w = t >> 6, lane = t & 63;
    if (lane == 0) red1[w] = s;
    __syncthreads();
    float mean = (red1[0] + red1[1] + red1[2] + red1[3]) * (1.f / 512.f);

    float d0 = a0 - mean, d1 = a1 - mean;
    float q = d0 * d0 + d1 * d1;
#pragma unroll
    for (int m = 32; m; m >>= 1) q += __shfl_xor(q, m, 64);
    if (lane == 0) red2[w] = q;
    __syncthreads();
    float var  = (red2[0] + red2[1] + red2[2] + red2[3]) * (1.f / 512.f);
    float rstd = rsqrtf(var + 1e-5f);

    float r0 = d0 * rstd * g[t]       + bb[t];
    float r1 = d1 * rstd * g[t + 256] + bb[t + 256];
    xo[t] = r0; xo[t + 256] = r1;
    short h0 = f2bf(r0); hh[t] = h0;       ll[t] = f2bf(r0 - bf2f(h0));
    short h1 = f2bf(r1); hh[t + 256] = h1; ll[t + 256] = f2bf(r1 - bf2f(h1));
}

// ---------------------------------------------------------------------------
extern "C" void kernel_launch(void* const* d_in, const int* in_sizes, int n_in,
                              void* d_out, int out_size, void* d_ws, size_t ws_size,
                              hipStream_t stream)
{
    const int*   tokens = (const int*)  d_in[0];
    const float* enc    = (const float*)d_in[1];
    const float* emb    = (const float*)d_in[3];
    const float* Wqkvo  = (const float*)d_in[4];   // [L,2,4,D,D]
    const float* bqkvo  = (const float*)d_in[5];   // [L,2,4,D]
    const float* W1     = (const float*)d_in[6];   // [L,D,DFF]
    const float* b1     = (const float*)d_in[7];
    const float* W2     = (const float*)d_in[8];   // [L,DFF,D]
    const float* b2     = (const float*)d_in[9];
    const float* lng    = (const float*)d_in[10];  // [L,3,D]
    const float* lnb    = (const float*)d_in[11];
    const float* Wout   = (const float*)d_in[12];  // [D,V]
    const float* bout   = (const float*)d_in[13];

    float* out    = (float*)d_out;
    float* selfA  = out + 65536000L;
    float* crossA = selfA + 67108864L;

    // workspace carve (~83 MB)
    char* p = (char*)d_ws;
    float* x    = (float*)p; p += 1048576L * 4;
    short* xh   = (short*)p; p += 1048576L * 2;
    short* xl   = (short*)p; p += 1048576L * 2;
    float* qkv  = (float*)p; p += 3145728L * 4;
    short* oh   = (short*)p; p += 1048576L * 2;
    short* ol   = (short*)p; p += 1048576L * 2;
    float* t1f  = (float*)p; p += 1048576L * 4;
    short* t1h  = (short*)p; p += 4194304L * 2;
    short* t1l  = (short*)p; p += 4194304L * 2;
    short* ench = (short*)p; p += 1048576L * 2;
    short* encl = (short*)p; p += 1048576L * 2;
    short* WTh  = (short*)p; p += 8192000L * 2;
    short* WTl  = (short*)p; p += 8192000L * 2;

    const long PW = 262144L;   // 512*512
    const long XS = 1048576L;  // 2048*512

    embed_pe_kernel<<<4096, 256, 0, stream>>>(tokens, emb, x, xh, xl);
    cvt_kernel<<<1024, 256, 0, stream>>>(enc, ench, encl);

    for (int l = 0; l < NLAYER; ++l) {
        const float* Wl = Wqkvo + (long)l * 2097152L;
        const float* bl = bqkvo + (long)l * 4096L;
        const float* g  = lng + (long)l * 3 * 512;
        const float* bb = lnb + (long)l * 3 * 512;

        // ---- self-attention ----
        wtrans_kernel<<<dim3(8, 8, 4), 256, 0, stream>>>(Wl, WTh, WTl, 512, 512, PW, PW);
        gemm_mfma_kernel<64,0,0><<<dim3(8, 32, 3), 256, 0, stream>>>(
            xh, xl, WTh, WTl, bl, qkv, nullptr, nullptr, 512, 512, PW, 512L, XS);
        attention_kernel<true><<<dim3(128, 8, 2), 256, 0, stream>>>(
            qkv, qkv + XS, qkv + 2 * XS, selfA + (long)l * 16777216L, oh, ol);
        gemm_mfma_kernel<64,0,0><<<dim3(8, 32, 1), 256, 0, stream>>>(
            oh, ol, WTh + 3 * PW, WTl + 3 * PW, bl + 3 * 512, t1f, nullptr, nullptr,
            512, 512, 0, 0, 0);
        add_ln_kernel<<<MROWS, 256, 0, stream>>>(x, t1f, g, bb, x, xh, xl);

        // ---- cross-attention ----
        const float* Wc = Wl + 4 * PW;
        const float* bc = bl + 2048;
        wtrans_kernel<<<dim3(8, 8, 4), 256, 0, stream>>>(Wc, WTh, WTl, 512, 512, PW, PW);
        gemm_mfma_kernel<64,0,0><<<dim3(8, 32, 1), 256, 0, stream>>>(
            xh, xl, WTh, WTl, bc, qkv, nullptr, nullptr, 512, 512, 0, 0, 0);
        gemm_mfma_kernel<64,0,0><<<dim3(8, 32, 2), 256, 0, stream>>>(
            ench, encl, WTh + PW, WTl + PW, bc + 512, qkv + XS, nullptr, nullptr,
            512, 512, PW, 512L, XS);
        attention_kernel<false><<<dim3(128, 8, 2), 256, 0, stream>>>(
            qkv, qkv + XS, qkv + 2 * XS, crossA + (long)l * 16777216L, oh, ol);
        gemm_mfma_kernel<64,0,0><<<dim3(8, 32, 1), 256, 0, stream>>>(
            oh, ol, WTh + 3 * PW, WTl + 3 * PW, bc + 3 * 512, t1f, nullptr, nullptr,
            512, 512, 0, 0, 0);
        add_ln_kernel<<<MROWS, 256, 0, stream>>>(x, t1f, g + 512, bb + 512, x, xh, xl);

        // ---- FFN ----
        wtrans_kernel<<<dim3(32, 8, 1), 256, 0, stream>>>(
            W1 + (long)l * 1048576L, WTh, WTl, 512, 2048, 0, 0);
        gemm_mfma_kernel<128,1,2><<<dim3(16, 16, 1), 256, 0, stream>>>(
            xh, xl, WTh, WTl, b1 + (long)l * 2048, nullptr, t1h, t1l,
            512, 2048, 0, 0, 0);
        wtrans_kernel<<<dim3(8, 32, 1), 256, 0, stream>>>(
            W2 + (long)l * 1048576L, WTh, WTl, 2048, 512, 0, 0);
        gemm_mfma_kernel<64,0,0><<<dim3(8, 32, 1), 256, 0, stream>>>(
            t1h, t1l, WTh, WTl, b2 + (long)l * 512, t1f, nullptr, nullptr,
            2048, 512, 0, 0, 0);
        add_ln_kernel<<<MROWS, 256, 0, stream>>>(x, t1f, g + 1024, bb + 1024, x, xh, xl);
    }

    // ---- final vocab projection, two 16000-wide chunks (keeps WT scratch small)
    for (int c = 0; c < 2; ++c) {
        wtrans_kernel<<<dim3(250, 8, 1), 256, 0, stream>>>(
            Wout + c * 16000, WTh, WTl, 512, VOCAB, 0, 0);
        gemm_mfma_kernel<128,0,0><<<dim3(125, 16, 1), 256, 0, stream>>>(
            xh, xl, WTh, WTl, bout + c * 16000, out + c * 16000, nullptr, nullptr,
            512, VOCAB, 0, 0, 0);
    }
}

// Round 3
// 1510.045 us; speedup vs baseline: 3.7355x; 2.3624x over previous
//
#include <hip/hip_runtime.h>
#include <hip/hip_bf16.h>

// ---------------------------------------------------------------------------
// Transformer decoder, fp32 I/O, split-bf16 MFMA everywhere (GEMMs + attention).
// B=2, ST=SS=1024, D=512, H=8, DK=64, L=4, DFF=2048, V=32000.
// ---------------------------------------------------------------------------

#define D_MODEL 512
#define NHEAD   8
#define DKH     64
#define SEQ     1024
#define NLAYER  4
#define DFF_    2048
#define VOCAB   32000
#define BATCH   2
#define MROWS   (BATCH*SEQ)   // 2048

typedef short bf16x8 __attribute__((ext_vector_type(8)));
typedef short short4v __attribute__((ext_vector_type(4)));
typedef float f32x4  __attribute__((ext_vector_type(4)));

static __device__ __forceinline__ short f2bf(float f) {
    __hip_bfloat16 h = __float2bfloat16(f);
    return *reinterpret_cast<short*>(&h);
}
static __device__ __forceinline__ float bf2f(short s) {
    __hip_bfloat16 h = *reinterpret_cast<__hip_bfloat16*>(&s);
    return __bfloat162float(h);
}
static __device__ __forceinline__ void gld16(const void* g, void* l) {
    __builtin_amdgcn_global_load_lds(
        (__attribute__((address_space(1))) void*)(void*)g,
        (__attribute__((address_space(3))) void*)l, 16, 0, 0);
}

// ---------------- embedding + positional encoding + hi/lo -------------------
__global__ __launch_bounds__(256) void embed_pe_kernel(
    const int* __restrict__ tokens, const float* __restrict__ emb,
    float* __restrict__ x, short* __restrict__ xh, short* __restrict__ xl)
{
    long idx = (long)blockIdx.x * 256 + threadIdx.x;   // over 1,048,576
    int  d   = (int)(idx & (D_MODEL - 1));
    long row = idx >> 9;
    int  s   = (int)(row & (SEQ - 1));
    int  tok = tokens[row];
    float twoi = (float)((d >> 1) << 1);
    float div  = expf(twoi * (-9.210340371976184f / 512.0f));
    float arg  = (float)s * div;
    float pe   = (d & 1) ? cosf(arg) : sinf(arg);
    float v = emb[(long)tok * D_MODEL + d] * 22.62741699796952f + pe; // sqrt(512)
    x[idx] = v;
    short h = f2bf(v);
    xh[idx] = h;
    xl[idx] = f2bf(v - bf2f(h));
}

// ---------------- fp32 -> bf16 hi/lo (straight layout) ----------------------
__global__ __launch_bounds__(256) void cvt_kernel(
    const float* __restrict__ in, short* __restrict__ h, short* __restrict__ l)
{
    long e = ((long)blockIdx.x * 256 + threadIdx.x) * 4;
    float4 v = *(const float4*)&in[e];
    float f[4] = {v.x, v.y, v.z, v.w};
#pragma unroll
    for (int i = 0; i < 4; ++i) {
        short hh = f2bf(f[i]);
        h[e + i] = hh;
        l[e + i] = f2bf(f[i] - bf2f(hh));
    }
}

// ---------------- weight transpose-convert: W[K,N] -> WT[N,K] hi/lo ---------
__global__ __launch_bounds__(256) void wtrans_kernel(
    const float* __restrict__ W, short* __restrict__ Th, short* __restrict__ Tl,
    int K, int ldW, long zW, long zT)
{
    long z = blockIdx.z;
    W  += z * zW;
    Th += z * zT;
    Tl += z * zT;
    const int n0 = blockIdx.x * 64, k0 = blockIdx.y * 64;
    __shared__ float tile[64][65];
    const int t = threadIdx.x;
#pragma unroll
    for (int i = 0; i < 4; ++i) {
        int e = t + i * 256; int kk = e >> 4; int nn = (e & 15) * 4;
        float4 v = *(const float4*)&W[(long)(k0 + kk) * ldW + n0 + nn];
        tile[kk][nn] = v.x; tile[kk][nn + 1] = v.y;
        tile[kk][nn + 2] = v.z; tile[kk][nn + 3] = v.w;
    }
    __syncthreads();
    const int n = t >> 2, ks = (t & 3) * 16;
    short h8[16], l8[16];
#pragma unroll
    for (int j = 0; j < 16; ++j) {
        float f = tile[ks + j][n];
        short h = f2bf(f);
        h8[j] = h;
        l8[j] = f2bf(f - bf2f(h));
    }
    long base = (long)(n0 + n) * K + k0 + ks;
    *(bf16x8*)&Th[base]     = *(bf16x8*)&h8[0];
    *(bf16x8*)&Th[base + 8] = *(bf16x8*)&h8[8];
    *(bf16x8*)&Tl[base]     = *(bf16x8*)&l8[0];
    *(bf16x8*)&Tl[base + 8] = *(bf16x8*)&l8[8];
}

// ---------------- split-bf16 MFMA GEMM --------------------------------------
// C[M,N] = act((Ah+Al)[M,K] @ (Bh+Bl)^T[N,K] + bias)   (3-product split)
// MODE 0: fp32 C.  MODE 2: bf16 hi/lo Ch/Cl.  MODE 3: head-major attention
// operand output [B,H,S,64] hi/lo, dk swizzled within 32-chunks, z scaled.
template<int BT, int ACT, int MODE>
__global__ __launch_bounds__(256) void gemm_mfma_kernel(
    const short* __restrict__ Ah, const short* __restrict__ Al,
    const short* __restrict__ Bh, const short* __restrict__ Bl,
    const float* __restrict__ bias, float* __restrict__ C,
    short* __restrict__ Ch, short* __restrict__ Cl,
    int K, int ldc, long zB, long zBias, long zC, int scaledZ)
{
    constexpr int HM = BT / 2;
    constexpr int MT = BT / 32;
    const long z = blockIdx.z;
    Bh += z * zB; Bl += z * zB; bias += z * zBias;

    const int n0 = blockIdx.x * BT, m0 = blockIdx.y * BT;
    const int t = threadIdx.x;
    const int w = t >> 6, lane = t & 63;
    const int wm = w >> 1, wn = w & 1;
    const int lr = lane & 15, ks = lane >> 4;

    __shared__ short sAh[BT * 32], sAl[BT * 32], sBh[BT * 32], sBl[BT * 32];

    f32x4 acc[MT][MT];
#pragma unroll
    for (int i = 0; i < MT; ++i)
#pragma unroll
        for (int j = 0; j < MT; ++j) acc[i][j] = (f32x4){0.f, 0.f, 0.f, 0.f};

    const long rowA = (long)m0 * K * 2;
    const long rowB = (long)n0 * K * 2;

    for (int k0 = 0; k0 < K; k0 += 32) {
#pragma unroll
        for (int i = 0; i < BT / 64; ++i) {
            const int  L = i * 4096 + t * 16;
            const int  r = L >> 6;
            const int  s = L & 63;
            const long gb = ((long)r * K + k0) * 2 + s;
            gld16((const char*)Ah + rowA + gb, (char*)sAh + L);
            gld16((const char*)Al + rowA + gb, (char*)sAl + L);
            gld16((const char*)Bh + rowB + gb, (char*)sBh + L);
            gld16((const char*)Bl + rowB + gb, (char*)sBl + L);
        }
        __syncthreads();

        bf16x8 ah[MT], al[MT], bh[MT], bl[MT];
#pragma unroll
        for (int mt = 0; mt < MT; ++mt) {
            int row = wm * HM + mt * 16 + lr;
            ah[mt] = *(const bf16x8*)&sAh[row * 32 + ks * 8];
            al[mt] = *(const bf16x8*)&sAl[row * 32 + ks * 8];
            int col = wn * HM + mt * 16 + lr;
            bh[mt] = *(const bf16x8*)&sBh[col * 32 + ks * 8];
            bl[mt] = *(const bf16x8*)&sBl[col * 32 + ks * 8];
        }
#pragma unroll
        for (int mt = 0; mt < MT; ++mt)
#pragma unroll
            for (int nt = 0; nt < MT; ++nt) {
                acc[mt][nt] = __builtin_amdgcn_mfma_f32_16x16x32_bf16(
                    ah[mt], bh[nt], acc[mt][nt], 0, 0, 0);
                acc[mt][nt] = __builtin_amdgcn_mfma_f32_16x16x32_bf16(
                    ah[mt], bl[nt], acc[mt][nt], 0, 0, 0);
                acc[mt][nt] = __builtin_amdgcn_mfma_f32_16x16x32_bf16(
                    al[mt], bh[nt], acc[mt][nt], 0, 0, 0);
            }
        __syncthreads();
    }

    const int rq = lane >> 4, cq = lane & 15;
#pragma unroll
    for (int mt = 0; mt < MT; ++mt)
#pragma unroll
        for (int nt = 0; nt < MT; ++nt) {
            int gr0 = m0 + wm * HM + mt * 16 + rq * 4;
            int gc  = n0 + wn * HM + nt * 16 + cq;
            float bv = bias[gc];
#pragma unroll
            for (int i = 0; i < 4; ++i) {
                float v = acc[mt][nt][i] + bv;
                if (ACT == 1) v = fmaxf(v, 0.f);
                if (MODE == 0) {
                    long off = (long)(gr0 + i) * ldc + gc + z * zC;
                    C[off] = v;
                } else if (MODE == 2) {
                    long off = (long)(gr0 + i) * ldc + gc + z * zC;
                    short h = f2bf(v);
                    Ch[off] = h;
                    Cl[off] = f2bf(v - bf2f(h));
                } else {           // MODE 3: head-major, swizzled dk
                    int gr = gr0 + i;
                    int b  = gr >> 10, s = gr & (SEQ - 1);
                    int hh = gc >> 6, dk = gc & 63;
                    float v2 = ((int)z == scaledZ) ? v * 0.125f : v;
                    int dks = (dk & 32) | ((dk & 31) ^ (((s >> 1) & 3) << 3));
                    long oidx = z * zC +
                        (((long)(b * NHEAD + hh)) * SEQ + s) * 64 + dks;
                    short h = f2bf(v2);
                    Ch[oidx] = h;
                    Cl[oidx] = f2bf(v2 - bf2f(h));
                }
            }
        }
}

// ---------------- QK^T MFMA: 64x64 score tiles, masked, scaled --------------
// Q pre-scaled by 1/8; Q/K stored head-major hi/lo with 32-chunk dk swizzle.
template<bool CAUSAL>
__global__ __launch_bounds__(256) void qk_kernel(
    const short* __restrict__ Qh, const short* __restrict__ Ql,
    const short* __restrict__ Kh, const short* __restrict__ Kl,
    float* __restrict__ scores)
{
    const int kt = blockIdx.x, qs = blockIdx.y, bh = blockIdx.z;
    const int t = threadIdx.x;

    if (CAUSAL && kt > qs) {              // fully masked tile
        float4 mval = {-1e9f, -1e9f, -1e9f, -1e9f};
#pragma unroll
        for (int i = 0; i < 4; ++i) {
            int f4 = t + 256 * i;
            int row = f4 >> 4, c4 = f4 & 15;
            *(float4*)&scores[((long)bh << 20) + ((long)(qs*64 + row) << 10)
                              + kt*64 + c4*4] = mval;
        }
        return;
    }

    __shared__ short sQh[64*32], sQl[64*32], sKh[64*32], sKl[64*32];
    const int lane = t & 63, w = t >> 6;
    const int wm = w >> 1, wn = w & 1, lr = lane & 15, ks = lane >> 4;

    f32x4 acc[2][2];
#pragma unroll
    for (int i = 0; i < 2; ++i)
#pragma unroll
        for (int j = 0; j < 2; ++j) acc[i][j] = (f32x4){0.f, 0.f, 0.f, 0.f};

    for (int k0 = 0; k0 < 64; k0 += 32) {
        const int r = t >> 2, off = (t & 3) * 16;
        long qsrc = (((long)bh * SEQ + qs*64 + r) * 64 + k0) * 2 + off;
        long ksrc = (((long)bh * SEQ + kt*64 + r) * 64 + k0) * 2 + off;
        gld16((const char*)Qh + qsrc, (char*)sQh + t*16);
        gld16((const char*)Ql + qsrc, (char*)sQl + t*16);
        gld16((const char*)Kh + ksrc, (char*)sKh + t*16);
        gld16((const char*)Kl + ksrc, (char*)sKl + t*16);
        __syncthreads();

        bf16x8 qa[2][2], ka[2][2];
#pragma unroll
        for (int mt = 0; mt < 2; ++mt) {
            int qr = wm*32 + mt*16 + lr;
            int qoff = qr*32 + ((ks*8) ^ (((qr >> 1) & 3) << 3));
            qa[mt][0] = *(const bf16x8*)&sQh[qoff];
            qa[mt][1] = *(const bf16x8*)&sQl[qoff];
            int kr = wn*32 + mt*16 + lr;
            int koff = kr*32 + ((ks*8) ^ (((kr >> 1) & 3) << 3));
            ka[mt][0] = *(const bf16x8*)&sKh[koff];
            ka[mt][1] = *(const bf16x8*)&sKl[koff];
        }
#pragma unroll
        for (int mt = 0; mt < 2; ++mt)
#pragma unroll
            for (int nt = 0; nt < 2; ++nt) {
                acc[mt][nt] = __builtin_amdgcn_mfma_f32_16x16x32_bf16(
                    qa[mt][0], ka[nt][0], acc[mt][nt], 0, 0, 0);
                acc[mt][nt] = __builtin_amdgcn_mfma_f32_16x16x32_bf16(
                    qa[mt][0], ka[nt][1], acc[mt][nt], 0, 0, 0);
                acc[mt][nt] = __builtin_amdgcn_mfma_f32_16x16x32_bf16(
                    qa[mt][1], ka[nt][0], acc[mt][nt], 0, 0, 0);
            }
        __syncthreads();
    }

    const int rq = lane >> 4, cq = lane & 15;
#pragma unroll
    for (int mt = 0; mt < 2; ++mt)
#pragma unroll
        for (int nt = 0; nt < 2; ++nt)
#pragma unroll
            for (int i = 0; i < 4; ++i) {
                int gq = qs*64 + wm*32 + mt*16 + rq*4 + i;
                int gk = kt*64 + wn*32 + nt*16 + cq;
                float v = acc[mt][nt][i];
                if (CAUSAL && gk > gq) v = -1e9f;
                scores[((long)bh << 20) + ((long)gq << 10) + gk] = v;
            }
}

// ---------------- V transpose: head-major V -> VT[bh][dk][s] (pre-swizzled) -
__global__ __launch_bounds__(256) void vtrans_kernel(
    const short* __restrict__ Vh, const short* __restrict__ Vl,
    short* __restrict__ VTh, short* __restrict__ VTl)
{
    const int strip = blockIdx.x, bh = blockIdx.y;
    __shared__ short th[64][72], tl[64][72];
    const int t = threadIdx.x;
    {
        const int s = t >> 2, g0 = (t & 3) * 2;
        long rowb = ((long)bh * SEQ + strip*64 + s) * 64;
        int sx = (s >> 1) & 3;
#pragma unroll
        for (int gg = 0; gg < 2; ++gg) {
            int g = g0 + gg;
            int gsw = (g & 4) | ((g & 3) ^ sx);   // undo MODE3 dk swizzle
            *(bf16x8*)&th[s][g*8] = *(const bf16x8*)&Vh[rowb + gsw*8];
            *(bf16x8*)&tl[s][g*8] = *(const bf16x8*)&Vl[rowb + gsw*8];
        }
    }
    __syncthreads();
    const int dk = t >> 2, s0 = (t & 3) * 16;
    const int swz = (((dk >> 1) & 3) << 3) | (((dk >> 3) & 1) << 5);
    long rowo = ((long)bh * 64 + dk) * 1024 + strip*64;
#pragma unroll
    for (int g = 0; g < 2; ++g) {
        int sl = s0 + g*8;
        short tmp_h[8], tmp_l[8];
#pragma unroll
        for (int j = 0; j < 8; ++j) { tmp_h[j] = th[sl+j][dk]; tmp_l[j] = tl[sl+j][dk]; }
        *(bf16x8*)&VTh[rowo + (sl ^ swz)] = *(bf16x8*)&tmp_h[0];
        *(bf16x8*)&VTl[rowo + (sl ^ swz)] = *(bf16x8*)&tmp_l[0];
    }
}

// ---------------- softmax + PV MFMA (64 q-rows per block) -------------------
template<bool CAUSAL>
__global__ __launch_bounds__(256) void pv_kernel(
    const float* __restrict__ scores, const short* __restrict__ VTh,
    const short* __restrict__ VTl, float* __restrict__ attn,
    short* __restrict__ Oh, short* __restrict__ Ol)
{
    const int strip = blockIdx.x, bh = blockIdx.y;
    __shared__ short sPh[64][72], sPl[64][72];
    __shared__ short sVh[64*64], sVl[64*64];
    const int t = threadIdx.x;
    const int q = t >> 2;
    const long rowbase = ((long)bh << 20) + ((long)(strip*64 + q) << 10);
    const float* srow = scores + rowbase;
    float* arow = attn + rowbase;

    // phase 1: online row max + sum(exp)
    float m = -3.0e38f, sum = 0.f;
    const int jlim = CAUSAL ? (strip + 1) * 4 : 64;
    for (int j = 0; j < jlim; ++j) {
        float4 v = *(const float4*)&srow[((t & 3) + 4*j) * 4];
        float m4 = fmaxf(fmaxf(v.x, v.y), fmaxf(v.z, v.w));
        float mn = fmaxf(m, m4);
        sum = sum * __expf(m - mn) + __expf(v.x - mn) + __expf(v.y - mn)
            + __expf(v.z - mn) + __expf(v.w - mn);
        m = mn;
    }
#pragma unroll
    for (int d = 1; d <= 2; d <<= 1) {
        float mo = __shfl_xor(m, d, 64);
        float so = __shfl_xor(sum, d, 64);
        float mn = fmaxf(m, mo);
        sum = sum * __expf(m - mn) + so * __expf(mo - mn);
        m = mn;
    }
    const float inv = 1.f / sum;

    const int w = t >> 6, lane = t & 63, lr = lane & 15, ks = lane >> 4;
    f32x4 acc[4];
#pragma unroll
    for (int nt = 0; nt < 4; ++nt) acc[nt] = (f32x4){0.f, 0.f, 0.f, 0.f};

    const int kcend = CAUSAL ? strip*64 + 64 : SEQ;

    for (int kc = 0; kc < SEQ; kc += 64) {
        if (kc >= kcend) {                 // fully masked: p == 0
            float4 z4 = {0.f, 0.f, 0.f, 0.f};
#pragma unroll
            for (int j = 0; j < 4; ++j)
                *(float4*)&arow[kc + ((t & 3) + 4*j)*4] = z4;
            continue;
        }
        // stage VT chunk (global data pre-swizzled -> linear copy)
#pragma unroll
        for (int i = 0; i < 2; ++i) {
            int L = i * 4096 + t * 16;
            int r = L >> 7, off = L & 127;
            long sb = (((long)bh * 64 + r) * 1024 + kc) * 2 + off;
            gld16((const char*)VTh + sb, (char*)sVh + L);
            gld16((const char*)VTl + sb, (char*)sVl + L);
        }
        // probabilities for this chunk
#pragma unroll
        for (int j = 0; j < 4; ++j) {
            int f4 = (t & 3) + 4*j;
            float4 v = *(const float4*)&srow[kc + f4*4];
            float4 p;
            p.x = __expf(v.x - m) * inv;
            p.y = __expf(v.y - m) * inv;
            p.z = __expf(v.z - m) * inv;
            p.w = __expf(v.w - m) * inv;
            *(float4*)&arow[kc + f4*4] = p;
            short4v hh, ll;
            hh.x = f2bf(p.x); ll.x = f2bf(p.x - bf2f(hh.x));
            hh.y = f2bf(p.y); ll.y = f2bf(p.y - bf2f(hh.y));
            hh.z = f2bf(p.z); ll.z = f2bf(p.z - bf2f(hh.z));
            hh.w = f2bf(p.w); ll.w = f2bf(p.w - bf2f(hh.w));
            *(short4v*)&sPh[q][f4*4] = hh;
            *(short4v*)&sPl[q][f4*4] = ll;
        }
        __syncthreads();
#pragma unroll
        for (int kstep = 0; kstep < 2; ++kstep) {
            int ar = w*16 + lr;
            bf16x8 pah = *(const bf16x8*)&sPh[ar][kstep*32 + ks*8];
            bf16x8 pal = *(const bf16x8*)&sPl[ar][kstep*32 + ks*8];
#pragma unroll
            for (int nt = 0; nt < 4; ++nt) {
                int dk = nt*16 + lr;
                int swz = (((dk >> 1) & 3) << 3) | (((dk >> 3) & 1) << 5);
                int koff = (kstep*32 + ks*8) ^ swz;
                bf16x8 vh8 = *(const bf16x8*)&sVh[dk*64 + koff];
                bf16x8 vl8 = *(const bf16x8*)&sVl[dk*64 + koff];
                acc[nt] = __builtin_amdgcn_mfma_f32_16x16x32_bf16(
                    pah, vh8, acc[nt], 0, 0, 0);
                acc[nt] = __builtin_amdgcn_mfma_f32_16x16x32_bf16(
                    pah, vl8, acc[nt], 0, 0, 0);
                acc[nt] = __builtin_amdgcn_mfma_f32_16x16x32_bf16(
                    pal, vh8, acc[nt], 0, 0, 0);
            }
        }
        __syncthreads();
    }

    const int rq = lane >> 4, cq = lane & 15;
    const int b = bh >> 3, hh_ = bh & 7;
#pragma unroll
    for (int nt = 0; nt < 4; ++nt)
#pragma unroll
        for (int i = 0; i < 4; ++i) {
            int row = w*16 + rq*4 + i;
            int dk = nt*16 + cq;
            float v = acc[nt][i];
            long oidx = ((long)(b * SEQ + strip*64 + row)) * D_MODEL + hh_*64 + dk;
            short h2 = f2bf(v);
            Oh[oidx] = h2;
            Ol[oidx] = f2bf(v - bf2f(h2));
        }
}

// ---------------- residual add + LayerNorm + hi/lo --------------------------
__global__ __launch_bounds__(256) void add_ln_kernel(
    const float* __restrict__ xin, const float* __restrict__ y,
    const float* __restrict__ g, const float* __restrict__ bb,
    float* __restrict__ xout, short* __restrict__ xh, short* __restrict__ xl)
{
    long row = blockIdx.x;
    const float* xr = xin + row * D_MODEL;
    const float* yr = y   + row * D_MODEL;
    float*       xo = xout+ row * D_MODEL;
    short*       hh = xh  + row * D_MODEL;
    short*       ll = xl  + row * D_MODEL;
    int t = threadIdx.x;

    float a0 = xr[t]       + yr[t];
    float a1 = xr[t + 256] + yr[t + 256];

    float s = a0 + a1;
#pragma unroll
    for (int m = 32; m; m >>= 1) s += __shfl_xor(s, m, 64);
    __shared__ float red1[4];
    __shared__ float red2[4];
    int w = t >> 6, lane = t & 63;
    if (lane == 0) red1[w] = s;
    __syncthreads();
    float mean = (red1[0] + red1[1] + red1[2] + red1[3]) * (1.f / 512.f);

    float d0 = a0 - mean, d1 = a1 - mean;
    float q = d0 * d0 + d1 * d1;
#pragma unroll
    for (int m = 32; m; m >>= 1) q += __shfl_xor(q, m, 64);
    if (lane == 0) red2[w] = q;
    __syncthreads();
    float var  = (red2[0] + red2[1] + red2[2] + red2[3]) * (1.f / 512.f);
    float rstd = rsqrtf(var + 1e-5f);

    float r0 = d0 * rstd * g[t]       + bb[t];
    float r1 = d1 * rstd * g[t + 256] + bb[t + 256];
    xo[t] = r0; xo[t + 256] = r1;
    short h0 = f2bf(r0); hh[t] = h0;       ll[t] = f2bf(r0 - bf2f(h0));
    short h1 = f2bf(r1); hh[t + 256] = h1; ll[t + 256] = f2bf(r1 - bf2f(h1));
}

// ---------------------------------------------------------------------------
extern "C" void kernel_launch(void* const* d_in, const int* in_sizes, int n_in,
                              void* d_out, int out_size, void* d_ws, size_t ws_size,
                              hipStream_t stream)
{
    const int*   tokens = (const int*)  d_in[0];
    const float* enc    = (const float*)d_in[1];
    const float* emb    = (const float*)d_in[3];
    const float* Wqkvo  = (const float*)d_in[4];   // [L,2,4,D,D]
    const float* bqkvo  = (const float*)d_in[5];   // [L,2,4,D]
    const float* W1     = (const float*)d_in[6];   // [L,D,DFF]
    const float* b1     = (const float*)d_in[7];
    const float* W2     = (const float*)d_in[8];   // [L,DFF,D]
    const float* b2     = (const float*)d_in[9];
    const float* lng    = (const float*)d_in[10];  // [L,3,D]
    const float* lnb    = (const float*)d_in[11];
    const float* Wout   = (const float*)d_in[12];  // [D,V]
    const float* bout   = (const float*)d_in[13];

    float* out    = (float*)d_out;
    float* selfA  = out + 65536000L;
    float* crossA = selfA + 67108864L;

    // workspace carve (~150 MB)
    char* p = (char*)d_ws;
    auto carve = [&](size_t bytes) { char* r = p; p += (bytes + 255) & ~255UL; return r; };
    float* x      = (float*)carve(1048576L * 4);
    short* xh     = (short*)carve(1048576L * 2);
    short* xl     = (short*)carve(1048576L * 2);
    short* ench   = (short*)carve(1048576L * 2);
    short* encl   = (short*)carve(1048576L * 2);
    short* qh     = (short*)carve(3145728L * 2);   // head-major Q|K|V hi
    short* ql     = (short*)carve(3145728L * 2);   // head-major Q|K|V lo
    short* vth    = (short*)carve(1048576L * 2);
    short* vtl    = (short*)carve(1048576L * 2);
    float* scores = (float*)carve(16777216L * 4);  // [B*H][S][S] 64 MB
    short* oh     = (short*)carve(1048576L * 2);
    short* ol     = (short*)carve(1048576L * 2);
    float* t1f    = (float*)carve(1048576L * 4);
    short* t1h    = (short*)carve(4194304L * 2);
    short* t1l    = (short*)carve(4194304L * 2);
    short* WTh    = (short*)carve(8192000L * 2);
    short* WTl    = (short*)carve(8192000L * 2);

    const long PW = 262144L;    // 512*512
    const long HS = 1048576L;   // B*H*S*64 per attention operand slab

    embed_pe_kernel<<<4096, 256, 0, stream>>>(tokens, emb, x, xh, xl);
    cvt_kernel<<<1024, 256, 0, stream>>>(enc, ench, encl);

    for (int l = 0; l < NLAYER; ++l) {
        const float* Wl = Wqkvo + (long)l * 2097152L;
        const float* bl = bqkvo + (long)l * 4096L;
        const float* g  = lng + (long)l * 3 * 512;
        const float* bb = lnb + (long)l * 3 * 512;

        // ---- self-attention ----
        wtrans_kernel<<<dim3(8, 8, 4), 256, 0, stream>>>(Wl, WTh, WTl, 512, 512, PW, PW);
        gemm_mfma_kernel<64,0,3><<<dim3(8, 32, 3), 256, 0, stream>>>(
            xh, xl, WTh, WTl, bl, nullptr, qh, ql, 512, 512, PW, 512L, HS, 0);
        qk_kernel<true><<<dim3(16, 16, 16), 256, 0, stream>>>(
            qh, ql, qh + HS, ql + HS, scores);
        vtrans_kernel<<<dim3(16, 16), 256, 0, stream>>>(
            qh + 2*HS, ql + 2*HS, vth, vtl);
        pv_kernel<true><<<dim3(16, 16), 256, 0, stream>>>(
            scores, vth, vtl, selfA + (long)l * 16777216L, oh, ol);
        gemm_mfma_kernel<64,0,0><<<dim3(8, 32, 1), 256, 0, stream>>>(
            oh, ol, WTh + 3*PW, WTl + 3*PW, bl + 3*512, t1f, nullptr, nullptr,
            512, 512, 0, 0, 0, -1);
        add_ln_kernel<<<MROWS, 256, 0, stream>>>(x, t1f, g, bb, x, xh, xl);

        // ---- cross-attention ----
        const float* Wc = Wl + 4 * PW;
        const float* bc = bl + 2048;
        wtrans_kernel<<<dim3(8, 8, 4), 256, 0, stream>>>(Wc, WTh, WTl, 512, 512, PW, PW);
        gemm_mfma_kernel<64,0,3><<<dim3(8, 32, 1), 256, 0, stream>>>(
            xh, xl, WTh, WTl, bc, nullptr, qh, ql, 512, 512, 0, 0, HS, 0);
        gemm_mfma_kernel<64,0,3><<<dim3(8, 32, 2), 256, 0, stream>>>(
            ench, encl, WTh + PW, WTl + PW, bc + 512, nullptr, qh + HS, ql + HS,
            512, 512, PW, 512L, HS, -1);
        qk_kernel<false><<<dim3(16, 16, 16), 256, 0, stream>>>(
            qh, ql, qh + HS, ql + HS, scores);
        vtrans_kernel<<<dim3(16, 16), 256, 0, stream>>>(
            qh + 2*HS, ql + 2*HS, vth, vtl);
        pv_kernel<false><<<dim3(16, 16), 256, 0, stream>>>(
            scores, vth, vtl, crossA + (long)l * 16777216L, oh, ol);
        gemm_mfma_kernel<64,0,0><<<dim3(8, 32, 1), 256, 0, stream>>>(
            oh, ol, WTh + 3*PW, WTl + 3*PW, bc + 3*512, t1f, nullptr, nullptr,
            512, 512, 0, 0, 0, -1);
        add_ln_kernel<<<MROWS, 256, 0, stream>>>(x, t1f, g + 512, bb + 512, x, xh, xl);

        // ---- FFN ----
        wtrans_kernel<<<dim3(32, 8, 1), 256, 0, stream>>>(
            W1 + (long)l * 1048576L, WTh, WTl, 512, 2048, 0, 0);
        gemm_mfma_kernel<128,1,2><<<dim3(16, 16, 1), 256, 0, stream>>>(
            xh, xl, WTh, WTl, b1 + (long)l * 2048, nullptr, t1h, t1l,
            512, 2048, 0, 0, 0, -1);
        wtrans_kernel<<<dim3(8, 32, 1), 256, 0, stream>>>(
            W2 + (long)l * 1048576L, WTh, WTl, 2048, 512, 0, 0);
        gemm_mfma_kernel<64,0,0><<<dim3(8, 32, 1), 256, 0, stream>>>(
            t1h, t1l, WTh, WTl, b2 + (long)l * 512, t1f, nullptr, nullptr,
            2048, 512, 0, 0, 0, -1);
        add_ln_kernel<<<MROWS, 256, 0, stream>>>(x, t1f, g + 1024, bb + 1024, x, xh, xl);
    }

    // ---- final vocab projection, two 16000-wide chunks ----
    for (int c = 0; c < 2; ++c) {
        wtrans_kernel<<<dim3(250, 8, 1), 256, 0, stream>>>(
            Wout + c * 16000, WTh, WTl, 512, VOCAB, 0, 0);
        gemm_mfma_kernel<128,0,0><<<dim3(125, 16, 1), 256, 0, stream>>>(
            xh, xl, WTh, WTl, bout + c * 16000, out + c * 16000, nullptr, nullptr,
            512, VOCAB, 0, 0, 0, -1);
    }
}

// Round 5
// 1507.971 us; speedup vs baseline: 3.7407x; 1.0014x over previous
//
#include <hip/hip_runtime.h>
#include <hip/hip_bf16.h>

// ---------------------------------------------------------------------------
// Transformer decoder, fp32 I/O, split-bf16 MFMA everywhere.
// Attention fully fused: QK^T -> online max/sum -> recompute -> probs + PV.
// B=2, ST=SS=1024, D=512, H=8, DK=64, L=4, DFF=2048, V=32000.
// ---------------------------------------------------------------------------

#define D_MODEL 512
#define NHEAD   8
#define DKH     64
#define SEQ     1024
#define NLAYER  4
#define DFF_    2048
#define VOCAB   32000
#define BATCH   2
#define MROWS   (BATCH*SEQ)   // 2048

typedef short bf16x8 __attribute__((ext_vector_type(8)));
typedef short short4v __attribute__((ext_vector_type(4)));
typedef float f32x4  __attribute__((ext_vector_type(4)));

static __device__ __forceinline__ short f2bf(float f) {
    __hip_bfloat16 h = __float2bfloat16(f);
    return *reinterpret_cast<short*>(&h);
}
static __device__ __forceinline__ float bf2f(short s) {
    __hip_bfloat16 h = *reinterpret_cast<__hip_bfloat16*>(&s);
    return __bfloat162float(h);
}
static __device__ __forceinline__ void gld16(const void* g, void* l) {
    __builtin_amdgcn_global_load_lds(
        (__attribute__((address_space(1))) void*)(void*)g,
        (__attribute__((address_space(3))) void*)l, 16, 0, 0);
}

// ---------------- embedding + positional encoding + hi/lo -------------------
__global__ __launch_bounds__(256) void embed_pe_kernel(
    const int* __restrict__ tokens, const float* __restrict__ emb,
    float* __restrict__ x, short* __restrict__ xh, short* __restrict__ xl)
{
    long idx = (long)blockIdx.x * 256 + threadIdx.x;   // over 1,048,576
    int  d   = (int)(idx & (D_MODEL - 1));
    long row = idx >> 9;
    int  s   = (int)(row & (SEQ - 1));
    int  tok = tokens[row];
    float twoi = (float)((d >> 1) << 1);
    float div  = expf(twoi * (-9.210340371976184f / 512.0f));
    float arg  = (float)s * div;
    float pe   = (d & 1) ? cosf(arg) : sinf(arg);
    float v = emb[(long)tok * D_MODEL + d] * 22.62741699796952f + pe; // sqrt(512)
    x[idx] = v;
    short h = f2bf(v);
    xh[idx] = h;
    xl[idx] = f2bf(v - bf2f(h));
}

// ---------------- fp32 -> bf16 hi/lo (straight layout) ----------------------
__global__ __launch_bounds__(256) void cvt_kernel(
    const float* __restrict__ in, short* __restrict__ h, short* __restrict__ l)
{
    long e = ((long)blockIdx.x * 256 + threadIdx.x) * 4;
    float4 v = *(const float4*)&in[e];
    float f[4] = {v.x, v.y, v.z, v.w};
#pragma unroll
    for (int i = 0; i < 4; ++i) {
        short hh = f2bf(f[i]);
        h[e + i] = hh;
        l[e + i] = f2bf(f[i] - bf2f(hh));
    }
}

// ---------------- weight transpose-convert: W[K,N] -> WT[N,K] hi/lo ---------
__global__ __launch_bounds__(256) void wtrans_kernel(
    const float* __restrict__ W, short* __restrict__ Th, short* __restrict__ Tl,
    int K, int ldW, long zW, long zT)
{
    long z = blockIdx.z;
    W  += z * zW;
    Th += z * zT;
    Tl += z * zT;
    const int n0 = blockIdx.x * 64, k0 = blockIdx.y * 64;
    __shared__ float tile[64][65];
    const int t = threadIdx.x;
#pragma unroll
    for (int i = 0; i < 4; ++i) {
        int e = t + i * 256; int kk = e >> 4; int nn = (e & 15) * 4;
        float4 v = *(const float4*)&W[(long)(k0 + kk) * ldW + n0 + nn];
        tile[kk][nn] = v.x; tile[kk][nn + 1] = v.y;
        tile[kk][nn + 2] = v.z; tile[kk][nn + 3] = v.w;
    }
    __syncthreads();
    const int n = t >> 2, ks = (t & 3) * 16;
    short h8[16], l8[16];
#pragma unroll
    for (int j = 0; j < 16; ++j) {
        float f = tile[ks + j][n];
        short h = f2bf(f);
        h8[j] = h;
        l8[j] = f2bf(f - bf2f(h));
    }
    long base = (long)(n0 + n) * K + k0 + ks;
    *(bf16x8*)&Th[base]     = *(bf16x8*)&h8[0];
    *(bf16x8*)&Th[base + 8] = *(bf16x8*)&h8[8];
    *(bf16x8*)&Tl[base]     = *(bf16x8*)&l8[0];
    *(bf16x8*)&Tl[base + 8] = *(bf16x8*)&l8[8];
}

// ---------------- split-bf16 MFMA GEMM --------------------------------------
// C[M,N] = act((Ah+Al)[M,K] @ (Bh+Bl)^T[N,K] + bias)   (3-product split)
// MODE 0: fp32 C.  MODE 2: bf16 hi/lo Ch/Cl.  MODE 3: head-major attention
// operand output [B,H,S,64] hi/lo with 3-bit dk XOR swizzle, z==scaledZ scaled.
template<int BT, int ACT, int MODE>
__global__ __launch_bounds__(256) void gemm_mfma_kernel(
    const short* __restrict__ Ah, const short* __restrict__ Al,
    const short* __restrict__ Bh, const short* __restrict__ Bl,
    const float* __restrict__ bias, float* __restrict__ C,
    short* __restrict__ Ch, short* __restrict__ Cl,
    int K, int ldc, long zB, long zBias, long zC, int scaledZ)
{
    constexpr int HM = BT / 2;
    constexpr int MT = BT / 32;
    const long z = blockIdx.z;
    Bh += z * zB; Bl += z * zB; bias += z * zBias;

    const int n0 = blockIdx.x * BT, m0 = blockIdx.y * BT;
    const int t = threadIdx.x;
    const int w = t >> 6, lane = t & 63;
    const int wm = w >> 1, wn = w & 1;
    const int lr = lane & 15, ks = lane >> 4;

    __shared__ short sAh[BT * 32], sAl[BT * 32], sBh[BT * 32], sBl[BT * 32];

    f32x4 acc[MT][MT];
#pragma unroll
    for (int i = 0; i < MT; ++i)
#pragma unroll
        for (int j = 0; j < MT; ++j) acc[i][j] = (f32x4){0.f, 0.f, 0.f, 0.f};

    const long rowA = (long)m0 * K * 2;
    const long rowB = (long)n0 * K * 2;

    for (int k0 = 0; k0 < K; k0 += 32) {
#pragma unroll
        for (int i = 0; i < BT / 64; ++i) {
            const int  L = i * 4096 + t * 16;
            const int  r = L >> 6;
            const int  s = L & 63;
            const long gb = ((long)r * K + k0) * 2 + s;
            gld16((const char*)Ah + rowA + gb, (char*)sAh + L);
            gld16((const char*)Al + rowA + gb, (char*)sAl + L);
            gld16((const char*)Bh + rowB + gb, (char*)sBh + L);
            gld16((const char*)Bl + rowB + gb, (char*)sBl + L);
        }
        __syncthreads();

        bf16x8 ah[MT], al[MT], bh[MT], bl[MT];
#pragma unroll
        for (int mt = 0; mt < MT; ++mt) {
            int row = wm * HM + mt * 16 + lr;
            ah[mt] = *(const bf16x8*)&sAh[row * 32 + ks * 8];
            al[mt] = *(const bf16x8*)&sAl[row * 32 + ks * 8];
            int col = wn * HM + mt * 16 + lr;
            bh[mt] = *(const bf16x8*)&sBh[col * 32 + ks * 8];
            bl[mt] = *(const bf16x8*)&sBl[col * 32 + ks * 8];
        }
#pragma unroll
        for (int mt = 0; mt < MT; ++mt)
#pragma unroll
            for (int nt = 0; nt < MT; ++nt) {
                acc[mt][nt] = __builtin_amdgcn_mfma_f32_16x16x32_bf16(
                    ah[mt], bh[nt], acc[mt][nt], 0, 0, 0);
                acc[mt][nt] = __builtin_amdgcn_mfma_f32_16x16x32_bf16(
                    ah[mt], bl[nt], acc[mt][nt], 0, 0, 0);
                acc[mt][nt] = __builtin_amdgcn_mfma_f32_16x16x32_bf16(
                    al[mt], bh[nt], acc[mt][nt], 0, 0, 0);
            }
        __syncthreads();
    }

    const int rq = lane >> 4, cq = lane & 15;
#pragma unroll
    for (int mt = 0; mt < MT; ++mt)
#pragma unroll
        for (int nt = 0; nt < MT; ++nt) {
            int gr0 = m0 + wm * HM + mt * 16 + rq * 4;
            int gc  = n0 + wn * HM + nt * 16 + cq;
            float bv = bias[gc];
#pragma unroll
            for (int i = 0; i < 4; ++i) {
                float v = acc[mt][nt][i] + bv;
                if (ACT == 1) v = fmaxf(v, 0.f);
                if (MODE == 0) {
                    long off = (long)(gr0 + i) * ldc + gc + z * zC;
                    C[off] = v;
                } else if (MODE == 2) {
                    long off = (long)(gr0 + i) * ldc + gc + z * zC;
                    short h = f2bf(v);
                    Ch[off] = h;
                    Cl[off] = f2bf(v - bf2f(h));
                } else {           // MODE 3: head-major, 3-bit dk swizzle
                    int gr = gr0 + i;
                    int b  = gr >> 10, s = gr & (SEQ - 1);
                    int hh = gc >> 6, dk = gc & 63;
                    float v2 = ((int)z == scaledZ) ? v * 0.125f : v;
                    int dks = dk ^ (((s >> 1) & 7) << 3);
                    long oidx = z * zC +
                        (((long)(b * NHEAD + hh)) * SEQ + s) * 64 + dks;
                    short h = f2bf(v2);
                    Ch[oidx] = h;
                    Cl[oidx] = f2bf(v2 - bf2f(h));
                }
            }
        }
}

// ---------------- V transpose: head-major V -> VT[bh][dk][s] (pre-swizzled) -
__global__ __launch_bounds__(256) void vtrans_kernel(
    const short* __restrict__ Vh, const short* __restrict__ Vl,
    short* __restrict__ VTh, short* __restrict__ VTl)
{
    const int strip = blockIdx.x, bh = blockIdx.y;
    __shared__ short th[64][72], tl[64][72];
    const int t = threadIdx.x;
    {
        const int s = t >> 2, g0 = (t & 3) * 2;
        long rowb = ((long)bh * SEQ + strip*64 + s) * 64;
        int sx = (s >> 1) & 7;
#pragma unroll
        for (int gg = 0; gg < 2; ++gg) {
            int g = g0 + gg;
            int gsw = g ^ sx;                      // undo MODE3 dk swizzle
            *(bf16x8*)&th[s][g*8] = *(const bf16x8*)&Vh[rowb + gsw*8];
            *(bf16x8*)&tl[s][g*8] = *(const bf16x8*)&Vl[rowb + gsw*8];
        }
    }
    __syncthreads();
    const int dk = t >> 2, s0 = (t & 3) * 16;
    const int swz = (((dk >> 1) & 3) << 3) | (((dk >> 3) & 1) << 5);
    long rowo = ((long)bh * 64 + dk) * 1024 + strip*64;
#pragma unroll
    for (int g = 0; g < 2; ++g) {
        int sl = s0 + g*8;
        short tmp_h[8], tmp_l[8];
#pragma unroll
        for (int j = 0; j < 8; ++j) { tmp_h[j] = th[sl+j][dk]; tmp_l[j] = tl[sl+j][dk]; }
        *(bf16x8*)&VTh[rowo + (sl ^ swz)] = *(bf16x8*)&tmp_h[0];
        *(bf16x8*)&VTl[rowo + (sl ^ swz)] = *(bf16x8*)&tmp_l[0];
    }
}

// ---------------- fused attention: QK -> online m/sum -> probs + PV ---------
// One block per (strip of 64 q-rows, bh). 4 waves, 16 q-rows each.
// Pass 1: MFMA scores per K-tile, online row max/sum (no storage).
// Pass 2: recompute scores, write probs to d_out, split-bf16 PV accumulate.
template<bool CAUSAL>
__global__ __launch_bounds__(256) void attn_fused_kernel(
    const short* __restrict__ Qh, const short* __restrict__ Ql,
    const short* __restrict__ Kh, const short* __restrict__ Kl,
    const short* __restrict__ VTh, const short* __restrict__ VTl,
    float* __restrict__ attn, short* __restrict__ Oh, short* __restrict__ Ol)
{
    const int strip = blockIdx.x, bh = blockIdx.y;
    const int q0 = strip * 64;
    const int t = threadIdx.x, w = t >> 6, lane = t & 63;
    const int lr = lane & 15, ks = lane >> 4;   // frag-read decomposition
    const int rq = lane >> 4, cq = lane & 15;   // C/D-layout decomposition
    const int sxq = (lr >> 1) & 7;              // 3-bit row swizzle selector

    __shared__ short sKh[2][64*64], sKl[2][64*64];   // 32 KB
    __shared__ short sVh[2][64*64], sVl[2][64*64];   // 32 KB
    __shared__ short sPh[4][16*80], sPl[4][16*80];   // 20.5 KB (wave-private)

    const int ktmax = CAUSAL ? strip + 1 : 16;

    // ---- Q frags to registers (stage via sVh/sVl, reused later) ----
    {
        const long qb = ((long)bh * SEQ + q0) * 128;
#pragma unroll
        for (int i2 = 0; i2 < 2; ++i2) {
            int L = i2 * 4096 + t * 16; int r = L >> 7, off = L & 127;
            gld16((const char*)Qh + qb + (long)r*128 + off, (char*)&sVh[0][0] + L);
            gld16((const char*)Ql + qb + (long)r*128 + off, (char*)&sVl[0][0] + L);
        }
    }
    __syncthreads();
    bf16x8 qa[2][2];   // [k0][hi/lo]
#pragma unroll
    for (int k0 = 0; k0 < 2; ++k0) {
        int o = (w*16 + lr) * 64 + ((k0*32 + ks*8) ^ (sxq << 3));
        qa[k0][0] = *(const bf16x8*)&sVh[0][o];
        qa[k0][1] = *(const bf16x8*)&sVl[0][o];
    }

    auto stageK = [&](int buf, int kt) {
        const long kb = ((long)bh * SEQ + kt*64) * 128;
#pragma unroll
        for (int i2 = 0; i2 < 2; ++i2) {
            int L = i2*4096 + t*16; int r = L >> 7, off = L & 127;
            gld16((const char*)Kh + kb + (long)r*128 + off, (char*)&sKh[buf][0] + L);
            gld16((const char*)Kl + kb + (long)r*128 + off, (char*)&sKl[buf][0] + L);
        }
    };
    auto stageV = [&](int buf, int kt) {
        const long vb = ((long)bh * 64) * 2048 + (long)kt * 128;
#pragma unroll
        for (int i2 = 0; i2 < 2; ++i2) {
            int L = i2*4096 + t*16; int r = L >> 7, off = L & 127;
            gld16((const char*)VTh + vb + (long)r*2048 + off, (char*)&sVh[buf][0] + L);
            gld16((const char*)VTl + vb + (long)r*2048 + off, (char*)&sVl[buf][0] + L);
        }
    };
    auto scoresOf = [&](int buf, int kt, f32x4* sc) {
#pragma unroll
        for (int nt = 0; nt < 4; ++nt) sc[nt] = (f32x4){0.f, 0.f, 0.f, 0.f};
#pragma unroll
        for (int k0 = 0; k0 < 2; ++k0) {
            bf16x8 kh[4], kl[4];
#pragma unroll
            for (int nt = 0; nt < 4; ++nt) {
                int o = (nt*16 + lr) * 64 + ((k0*32 + ks*8) ^ (sxq << 3));
                kh[nt] = *(const bf16x8*)&sKh[buf][o];
                kl[nt] = *(const bf16x8*)&sKl[buf][o];
            }
#pragma unroll
            for (int nt = 0; nt < 4; ++nt) {
                sc[nt] = __builtin_amdgcn_mfma_f32_16x16x32_bf16(
                    qa[k0][0], kh[nt], sc[nt], 0, 0, 0);
                sc[nt] = __builtin_amdgcn_mfma_f32_16x16x32_bf16(
                    qa[k0][0], kl[nt], sc[nt], 0, 0, 0);
                sc[nt] = __builtin_amdgcn_mfma_f32_16x16x32_bf16(
                    qa[k0][1], kh[nt], sc[nt], 0, 0, 0);
            }
        }
        if (CAUSAL && kt == strip) {
            int row = q0 + w*16 + rq*4;
#pragma unroll
            for (int nt = 0; nt < 4; ++nt) {
                int col = kt*64 + nt*16 + cq;
#pragma unroll
                for (int i = 0; i < 4; ++i)
                    if (col > row + i) sc[nt][i] = -1e9f;
            }
        }
    };

    // ---- pass 1: online max + sum ----
    float m[4]   = {-3e38f, -3e38f, -3e38f, -3e38f};
    float sum[4] = {0.f, 0.f, 0.f, 0.f};
    int cur = 0;
    stageK(0, 0);
    __syncthreads();
    for (int kt = 0; kt < ktmax; ++kt) {
        if (kt + 1 < ktmax) stageK(cur ^ 1, kt + 1);
        f32x4 sc[4];
        scoresOf(cur, kt, sc);
#pragma unroll
        for (int i = 0; i < 4; ++i) {
            float tm = fmaxf(fmaxf(sc[0][i], sc[1][i]), fmaxf(sc[2][i], sc[3][i]));
#pragma unroll
            for (int d2 = 1; d2 <= 8; d2 <<= 1) tm = fmaxf(tm, __shfl_xor(tm, d2, 64));
            float mn = fmaxf(m[i], tm);
            float ps = __expf(sc[0][i] - mn) + __expf(sc[1][i] - mn)
                     + __expf(sc[2][i] - mn) + __expf(sc[3][i] - mn);
#pragma unroll
            for (int d2 = 1; d2 <= 8; d2 <<= 1) ps += __shfl_xor(ps, d2, 64);
            sum[i] = sum[i] * __expf(m[i] - mn) + ps;
            m[i] = mn;
        }
        __syncthreads();
        cur ^= 1;
    }
    float inv[4];
#pragma unroll
    for (int i = 0; i < 4; ++i) inv[i] = 1.f / sum[i];

    // ---- pass 2: recompute, probs out, PV ----
    f32x4 acco[4];
#pragma unroll
    for (int nt = 0; nt < 4; ++nt) acco[nt] = (f32x4){0.f, 0.f, 0.f, 0.f};

    cur = 0;
    stageK(0, 0); stageV(0, 0);
    __syncthreads();
    for (int kt = 0; kt < 16; ++kt) {
        if (kt >= ktmax) {                      // causal: p == 0
#pragma unroll
            for (int nt = 0; nt < 4; ++nt)
#pragma unroll
                for (int i = 0; i < 4; ++i)
                    attn[((long)bh << 20) + ((long)(q0 + w*16 + rq*4 + i) << 10)
                         + kt*64 + nt*16 + cq] = 0.f;
            continue;
        }
        if (kt + 1 < ktmax) { stageK(cur ^ 1, kt + 1); stageV(cur ^ 1, kt + 1); }
        f32x4 sc[4];
        scoresOf(cur, kt, sc);
#pragma unroll
        for (int nt = 0; nt < 4; ++nt)
#pragma unroll
            for (int i = 0; i < 4; ++i) {
                float p = __expf(sc[nt][i] - m[i]) * inv[i];
                attn[((long)bh << 20) + ((long)(q0 + w*16 + rq*4 + i) << 10)
                     + kt*64 + nt*16 + cq] = p;
                short ph = f2bf(p);
                sPh[w][(rq*4 + i)*80 + nt*16 + cq] = ph;
                sPl[w][(rq*4 + i)*80 + nt*16 + cq] = f2bf(p - bf2f(ph));
            }
        // PV (P is wave-private; compiler inserts lgkm waits)
#pragma unroll
        for (int k0 = 0; k0 < 2; ++k0) {
            bf16x8 pah = *(const bf16x8*)&sPh[w][lr*80 + k0*32 + ks*8];
            bf16x8 pal = *(const bf16x8*)&sPl[w][lr*80 + k0*32 + ks*8];
#pragma unroll
            for (int nt = 0; nt < 4; ++nt) {
                int dk = nt*16 + lr;
                int swz = (((dk >> 1) & 3) << 3) | (((dk >> 3) & 1) << 5);
                int koff = (k0*32 + ks*8) ^ swz;
                bf16x8 vh8 = *(const bf16x8*)&sVh[cur][dk*64 + koff];
                bf16x8 vl8 = *(const bf16x8*)&sVl[cur][dk*64 + koff];
                acco[nt] = __builtin_amdgcn_mfma_f32_16x16x32_bf16(
                    pah, vh8, acco[nt], 0, 0, 0);
                acco[nt] = __builtin_amdgcn_mfma_f32_16x16x32_bf16(
                    pah, vl8, acco[nt], 0, 0, 0);
                acco[nt] = __builtin_amdgcn_mfma_f32_16x16x32_bf16(
                    pal, vh8, acco[nt], 0, 0, 0);
            }
        }
        __syncthreads();
        cur ^= 1;
    }

    const int b = bh >> 3, hh_ = bh & 7;
#pragma unroll
    for (int nt = 0; nt < 4; ++nt)
#pragma unroll
        for (int i = 0; i < 4; ++i) {
            float v = acco[nt][i];
            long oidx = ((long)(b * SEQ + q0 + w*16 + rq*4 + i)) * D_MODEL
                      + hh_*64 + nt*16 + cq;
            short h2 = f2bf(v);
            Oh[oidx] = h2;
            Ol[oidx] = f2bf(v - bf2f(h2));
        }
}

// ---------------- residual add + LayerNorm + hi/lo --------------------------
__global__ __launch_bounds__(256) void add_ln_kernel(
    const float* __restrict__ xin, const float* __restrict__ y,
    const float* __restrict__ g, const float* __restrict__ bb,
    float* __restrict__ xout, short* __restrict__ xh, short* __restrict__ xl)
{
    long row = blockIdx.x;
    const float* xr = xin + row * D_MODEL;
    const float* yr = y   + row * D_MODEL;
    float*       xo = xout+ row * D_MODEL;
    short*       hh = xh  + row * D_MODEL;
    short*       ll = xl  + row * D_MODEL;
    int t = threadIdx.x;

    float a0 = xr[t]       + yr[t];
    float a1 = xr[t + 256] + yr[t + 256];

    float s = a0 + a1;
#pragma unroll
    for (int m = 32; m; m >>= 1) s += __shfl_xor(s, m, 64);
    __shared__ float red1[4];
    __shared__ float red2[4];
    int w = t >> 6, lane = t & 63;
    if (lane == 0) red1[w] = s;
    __syncthreads();
    float mean = (red1[0] + red1[1] + red1[2] + red1[3]) * (1.f / 512.f);

    float d0 = a0 - mean, d1 = a1 - mean;
    float q = d0 * d0 + d1 * d1;
#pragma unroll
    for (int m = 32; m; m >>= 1) q += __shfl_xor(q, m, 64);
    if (lane == 0) red2[w] = q;
    __syncthreads();
    float var  = (red2[0] + red2[1] + red2[2] + red2[3]) * (1.f / 512.f);
    float rstd = rsqrtf(var + 1e-5f);

    float r0 = d0 * rstd * g[t]       + bb[t];
    float r1 = d1 * rstd * g[t + 256] + bb[t + 256];
    xo[t] = r0; xo[t + 256] = r1;
    short h0 = f2bf(r0); hh[t] = h0;       ll[t] = f2bf(r0 - bf2f(h0));
    short h1 = f2bf(r1); hh[t + 256] = h1; ll[t + 256] = f2bf(r1 - bf2f(h1));
}

// ---------------------------------------------------------------------------
extern "C" void kernel_launch(void* const* d_in, const int* in_sizes, int n_in,
                              void* d_out, int out_size, void* d_ws, size_t ws_size,
                              hipStream_t stream)
{
    const int*   tokens = (const int*)  d_in[0];
    const float* enc    = (const float*)d_in[1];
    const float* emb    = (const float*)d_in[3];
    const float* Wqkvo  = (const float*)d_in[4];   // [L,2,4,D,D]
    const float* bqkvo  = (const float*)d_in[5];   // [L,2,4,D]
    const float* W1     = (const float*)d_in[6];   // [L,D,DFF]
    const float* b1     = (const float*)d_in[7];
    const float* W2     = (const float*)d_in[8];   // [L,DFF,D]
    const float* b2     = (const float*)d_in[9];
    const float* lng    = (const float*)d_in[10];  // [L,3,D]
    const float* lnb    = (const float*)d_in[11];
    const float* Wout   = (const float*)d_in[12];  // [D,V]
    const float* bout   = (const float*)d_in[13];

    float* out    = (float*)d_out;
    float* selfA  = out + 65536000L;
    float* crossA = selfA + 67108864L;

    // workspace carve (~86 MB)
    char* p = (char*)d_ws;
    auto carve = [&](size_t bytes) { char* r = p; p += (bytes + 255) & ~255UL; return r; };
    float* x      = (float*)carve(1048576L * 4);
    short* xh     = (short*)carve(1048576L * 2);
    short* xl     = (short*)carve(1048576L * 2);
    short* ench   = (short*)carve(1048576L * 2);
    short* encl   = (short*)carve(1048576L * 2);
    short* qh     = (short*)carve(3145728L * 2);   // head-major Q|K|V hi
    short* ql     = (short*)carve(3145728L * 2);   // head-major Q|K|V lo
    short* vth    = (short*)carve(1048576L * 2);
    short* vtl    = (short*)carve(1048576L * 2);
    short* oh     = (short*)carve(1048576L * 2);
    short* ol     = (short*)carve(1048576L * 2);
    float* t1f    = (float*)carve(1048576L * 4);
    short* t1h    = (short*)carve(4194304L * 2);
    short* t1l    = (short*)carve(4194304L * 2);
    short* WTh    = (short*)carve(8192000L * 2);
    short* WTl    = (short*)carve(8192000L * 2);

    const long PW = 262144L;    // 512*512
    const long HS = 1048576L;   // B*H*S*64 per attention operand slab

    embed_pe_kernel<<<4096, 256, 0, stream>>>(tokens, emb, x, xh, xl);
    cvt_kernel<<<1024, 256, 0, stream>>>(enc, ench, encl);

    for (int l = 0; l < NLAYER; ++l) {
        const float* Wl = Wqkvo + (long)l * 2097152L;
        const float* bl = bqkvo + (long)l * 4096L;
        const float* g  = lng + (long)l * 3 * 512;
        const float* bb = lnb + (long)l * 3 * 512;

        // ---- self-attention ----
        wtrans_kernel<<<dim3(8, 8, 4), 256, 0, stream>>>(Wl, WTh, WTl, 512, 512, PW, PW);
        gemm_mfma_kernel<64,0,3><<<dim3(8, 32, 3), 256, 0, stream>>>(
            xh, xl, WTh, WTl, bl, nullptr, qh, ql, 512, 512, PW, 512L, HS, 0);
        vtrans_kernel<<<dim3(16, 16), 256, 0, stream>>>(
            qh + 2*HS, ql + 2*HS, vth, vtl);
        attn_fused_kernel<true><<<dim3(16, 16), 256, 0, stream>>>(
            qh, ql, qh + HS, ql + HS, vth, vtl,
            selfA + (long)l * 16777216L, oh, ol);
        gemm_mfma_kernel<64,0,0><<<dim3(8, 32, 1), 256, 0, stream>>>(
            oh, ol, WTh + 3*PW, WTl + 3*PW, bl + 3*512, t1f, nullptr, nullptr,
            512, 512, 0, 0, 0, -1);
        add_ln_kernel<<<MROWS, 256, 0, stream>>>(x, t1f, g, bb, x, xh, xl);

        // ---- cross-attention ----
        const float* Wc = Wl + 4 * PW;
        const float* bc = bl + 2048;
        wtrans_kernel<<<dim3(8, 8, 4), 256, 0, stream>>>(Wc, WTh, WTl, 512, 512, PW, PW);
        gemm_mfma_kernel<64,0,3><<<dim3(8, 32, 1), 256, 0, stream>>>(
            xh, xl, WTh, WTl, bc, nullptr, qh, ql, 512, 512, 0, 0, HS, 0);
        gemm_mfma_kernel<64,0,3><<<dim3(8, 32, 2), 256, 0, stream>>>(
            ench, encl, WTh + PW, WTl + PW, bc + 512, nullptr, qh + HS, ql + HS,
            512, 512, PW, 512L, HS, -1);
        vtrans_kernel<<<dim3(16, 16), 256, 0, stream>>>(
            qh + 2*HS, ql + 2*HS, vth, vtl);
        attn_fused_kernel<false><<<dim3(16, 16), 256, 0, stream>>>(
            qh, ql, qh + HS, ql + HS, vth, vtl,
            crossA + (long)l * 16777216L, oh, ol);
        gemm_mfma_kernel<64,0,0><<<dim3(8, 32, 1), 256, 0, stream>>>(
            oh, ol, WTh + 3*PW, WTl + 3*PW, bc + 3*512, t1f, nullptr, nullptr,
            512, 512, 0, 0, 0, -1);
        add_ln_kernel<<<MROWS, 256, 0, stream>>>(x, t1f, g + 512, bb + 512, x, xh, xl);

        // ---- FFN ----
        wtrans_kernel<<<dim3(32, 8, 1), 256, 0, stream>>>(
            W1 + (long)l * 1048576L, WTh, WTl, 512, 2048, 0, 0);
        gemm_mfma_kernel<128,1,2><<<dim3(16, 16, 1), 256, 0, stream>>>(
            xh, xl, WTh, WTl, b1 + (long)l * 2048, nullptr, t1h, t1l,
            512, 2048, 0, 0, 0, -1);
        wtrans_kernel<<<dim3(8, 32, 1), 256, 0, stream>>>(
            W2 + (long)l * 1048576L, WTh, WTl, 2048, 512, 0, 0);
        gemm_mfma_kernel<64,0,0><<<dim3(8, 32, 1), 256, 0, stream>>>(
            t1h, t1l, WTh, WTl, b2 + (long)l * 512, t1f, nullptr, nullptr,
            2048, 512, 0, 0, 0, -1);
        add_ln_kernel<<<MROWS, 256, 0, stream>>>(x, t1f, g + 1024, bb + 1024, x, xh, xl);
    }

    // ---- final vocab projection, two 16000-wide chunks ----
    for (int c = 0; c < 2; ++c) {
        wtrans_kernel<<<dim3(250, 8, 1), 256, 0, stream>>>(
            Wout + c * 16000, WTh, WTl, 512, VOCAB, 0, 0);
        gemm_mfma_kernel<128,0,0><<<dim3(125, 16, 1), 256, 0, stream>>>(
            xh, xl, WTh, WTl, bout + c * 16000, out + c * 16000, nullptr, nullptr,
            512, VOCAB, 0, 0, 0, -1);
    }
}

// Round 8
// 1379.879 us; speedup vs baseline: 4.0879x; 1.0928x over previous
//
#include <hip/hip_runtime.h>
#include <hip/hip_bf16.h>

// ---------------------------------------------------------------------------
// Transformer decoder, fp32 I/O, split-bf16 MFMA everywhere.
// Occupancy round: K-split GEMMs, 2-blocks/CU fused attention, fused V-transpose,
// merged per-layer weight transposes.
// B=2, ST=SS=1024, D=512, H=8, DK=64, L=4, DFF=2048, V=32000.
// ---------------------------------------------------------------------------

#define D_MODEL 512
#define NHEAD   8
#define DKH     64
#define SEQ     1024
#define NLAYER  4
#define DFF_    2048
#define VOCAB   32000
#define BATCH   2
#define MROWS   (BATCH*SEQ)   // 2048

typedef short bf16x8 __attribute__((ext_vector_type(8)));
typedef short short4v __attribute__((ext_vector_type(4)));
typedef float f32x4  __attribute__((ext_vector_type(4)));

static __device__ __forceinline__ short f2bf(float f) {
    __hip_bfloat16 h = __float2bfloat16(f);
    return *reinterpret_cast<short*>(&h);
}
static __device__ __forceinline__ float bf2f(short s) {
    __hip_bfloat16 h = *reinterpret_cast<__hip_bfloat16*>(&s);
    return __bfloat162float(h);
}
static __device__ __forceinline__ void gld16(const void* g, void* l) {
    __builtin_amdgcn_global_load_lds(
        (__attribute__((address_space(1))) void*)(void*)g,
        (__attribute__((address_space(3))) void*)l, 16, 0, 0);
}

// ---------------- embedding + positional encoding + hi/lo -------------------
__global__ __launch_bounds__(256) void embed_pe_kernel(
    const int* __restrict__ tokens, const float* __restrict__ emb,
    float* __restrict__ x, short* __restrict__ xh, short* __restrict__ xl)
{
    long idx = (long)blockIdx.x * 256 + threadIdx.x;   // over 1,048,576
    int  d   = (int)(idx & (D_MODEL - 1));
    long row = idx >> 9;
    int  s   = (int)(row & (SEQ - 1));
    int  tok = tokens[row];
    float twoi = (float)((d >> 1) << 1);
    float div  = expf(twoi * (-9.210340371976184f / 512.0f));
    float arg  = (float)s * div;
    float pe   = (d & 1) ? cosf(arg) : sinf(arg);
    float v = emb[(long)tok * D_MODEL + d] * 22.62741699796952f + pe; // sqrt(512)
    x[idx] = v;
    short h = f2bf(v);
    xh[idx] = h;
    xl[idx] = f2bf(v - bf2f(h));
}

// ---------------- fp32 -> bf16 hi/lo ----------------------------------------
__global__ __launch_bounds__(256) void cvt_kernel(
    const float* __restrict__ in, short* __restrict__ h, short* __restrict__ l)
{
    long e = ((long)blockIdx.x * 256 + threadIdx.x) * 4;
    float4 v = *(const float4*)&in[e];
    float f[4] = {v.x, v.y, v.z, v.w};
#pragma unroll
    for (int i = 0; i < 4; ++i) {
        short hh = f2bf(f[i]);
        h[e + i] = hh;
        l[e + i] = f2bf(f[i] - bf2f(hh));
    }
}

// ---------------- weight transpose-convert: W[K,N] -> WT[N,K] hi/lo ---------
// standalone (vocab chunks)
__global__ __launch_bounds__(256) void wtrans_kernel(
    const float* __restrict__ W, short* __restrict__ Th, short* __restrict__ Tl,
    int K, int ldW)
{
    const int n0 = blockIdx.x * 64, k0 = blockIdx.y * 64;
    __shared__ float tile[64][65];
    const int t = threadIdx.x;
#pragma unroll
    for (int i = 0; i < 4; ++i) {
        int e = t + i * 256; int kk = e >> 4; int nn = (e & 15) * 4;
        float4 v = *(const float4*)&W[(long)(k0 + kk) * ldW + n0 + nn];
        tile[kk][nn] = v.x; tile[kk][nn + 1] = v.y;
        tile[kk][nn + 2] = v.z; tile[kk][nn + 3] = v.w;
    }
    __syncthreads();
    const int n = t >> 2, ks = (t & 3) * 16;
    short h8[16], l8[16];
#pragma unroll
    for (int j = 0; j < 16; ++j) {
        float f = tile[ks + j][n];
        short h = f2bf(f);
        h8[j] = h;
        l8[j] = f2bf(f - bf2f(h));
    }
    long base = (long)(n0 + n) * K + k0 + ks;
    *(bf16x8*)&Th[base]     = *(bf16x8*)&h8[0];
    *(bf16x8*)&Th[base + 8] = *(bf16x8*)&h8[8];
    *(bf16x8*)&Tl[base]     = *(bf16x8*)&l8[0];
    *(bf16x8*)&Tl[base + 8] = *(bf16x8*)&l8[8];
}

// ---------------- merged per-layer weight transpose (10 matrices) -----------
// j<512: qkvo self+cross (8 mats x 64 tiles); 512..768: W1; 768..1024: W2
__global__ __launch_bounds__(256) void wtrans_layer_kernel(
    const float* __restrict__ Wqkvo, const float* __restrict__ W1,
    const float* __restrict__ W2, int l,
    short* __restrict__ Th, short* __restrict__ Tl)
{
    const int j = blockIdx.x;
    const float* W; int ldW, K; long dstOff; int n0, k0;
    if (j < 512) {
        int mat = j >> 6, tile_ = j & 63;
        W = Wqkvo + (long)l * 2097152L + (long)mat * 262144L;
        ldW = 512; K = 512; dstOff = (long)mat * 262144L;
        n0 = (tile_ & 7) * 64; k0 = (tile_ >> 3) * 64;
    } else if (j < 768) {
        int t2 = j - 512;
        W = W1 + (long)l * 1048576L; ldW = 2048; K = 512; dstOff = 2097152L;
        n0 = (t2 & 31) * 64; k0 = (t2 >> 5) * 64;
    } else {
        int t3 = j - 768;
        W = W2 + (long)l * 1048576L; ldW = 512; K = 2048; dstOff = 3145728L;
        n0 = (t3 & 7) * 64; k0 = (t3 >> 3) * 64;
    }
    __shared__ float tile[64][65];
    const int t = threadIdx.x;
#pragma unroll
    for (int i = 0; i < 4; ++i) {
        int e = t + i * 256; int kk = e >> 4; int nn = (e & 15) * 4;
        float4 v = *(const float4*)&W[(long)(k0 + kk) * ldW + n0 + nn];
        tile[kk][nn] = v.x; tile[kk][nn + 1] = v.y;
        tile[kk][nn + 2] = v.z; tile[kk][nn + 3] = v.w;
    }
    __syncthreads();
    const int n = t >> 2, ks = (t & 3) * 16;
    short h8[16], l8[16];
#pragma unroll
    for (int j2 = 0; j2 < 16; ++j2) {
        float f = tile[ks + j2][n];
        short h = f2bf(f);
        h8[j2] = h;
        l8[j2] = f2bf(f - bf2f(h));
    }
    long base = dstOff + (long)(n0 + n) * K + k0 + ks;
    *(bf16x8*)&Th[base]     = *(bf16x8*)&h8[0];
    *(bf16x8*)&Th[base + 8] = *(bf16x8*)&h8[8];
    *(bf16x8*)&Tl[base]     = *(bf16x8*)&l8[0];
    *(bf16x8*)&Tl[base + 8] = *(bf16x8*)&l8[8];
}

// ---------------- split-bf16 MFMA GEMM --------------------------------------
// C[M,N] = act((Ah+Al)[M,Keff]@(Bh+Bl)^T + bias), rows stride ldA/ldB, K-window
// at z*kOff. MODE 0: fp32+bias. MODE 2: bf16 hi/lo+bias(+relu). MODE 3: head-
// major attention operand w/ dk swizzle (z==vtZ -> direct transposed V write;
// z==scaledZ -> *0.125). MODE 5: fp32 partial, no bias.
template<int BT, int ACT, int MODE>
__global__ __launch_bounds__(256) void gemm_mfma_kernel(
    const short* __restrict__ Ah, const short* __restrict__ Al,
    const short* __restrict__ Bh, const short* __restrict__ Bl,
    const float* __restrict__ bias, float* __restrict__ C,
    short* __restrict__ Ch, short* __restrict__ Cl,
    short* __restrict__ VTh, short* __restrict__ VTl,
    int Keff, int ldA, int ldB, int ldc,
    long zB, long zBias, long zC, int kOff, int scaledZ, int vtZ)
{
    constexpr int HM = BT / 2;
    constexpr int MT = BT / 32;
    const long z = blockIdx.z;
    Bh += z * zB; Bl += z * zB;
    if (MODE != 5) bias += z * zBias;

    const int n0 = blockIdx.x * BT, m0 = blockIdx.y * BT;
    const int t = threadIdx.x;
    const int w = t >> 6, lane = t & 63;
    const int wm = w >> 1, wn = w & 1;
    const int lr = lane & 15, ks = lane >> 4;

    __shared__ short sAh[BT * 32], sAl[BT * 32], sBh[BT * 32], sBl[BT * 32];

    f32x4 acc[MT][MT];
#pragma unroll
    for (int i = 0; i < MT; ++i)
#pragma unroll
        for (int j = 0; j < MT; ++j) acc[i][j] = (f32x4){0.f, 0.f, 0.f, 0.f};

    const long rowA = ((long)m0 * ldA + (long)z * kOff) * 2;   // bytes
    const long rowB = ((long)n0 * ldB + (long)z * kOff) * 2;

    for (int k0 = 0; k0 < Keff; k0 += 32) {
#pragma unroll
        for (int i = 0; i < BT / 64; ++i) {
            const int  L = i * 4096 + t * 16;
            const int  r = L >> 6;
            const int  s = L & 63;
            const long gbA = ((long)r * ldA + k0) * 2 + s;
            const long gbB = ((long)r * ldB + k0) * 2 + s;
            gld16((const char*)Ah + rowA + gbA, (char*)sAh + L);
            gld16((const char*)Al + rowA + gbA, (char*)sAl + L);
            gld16((const char*)Bh + rowB + gbB, (char*)sBh + L);
            gld16((const char*)Bl + rowB + gbB, (char*)sBl + L);
        }
        __syncthreads();

        bf16x8 ah[MT], al[MT], bh[MT], bl[MT];
#pragma unroll
        for (int mt = 0; mt < MT; ++mt) {
            int row = wm * HM + mt * 16 + lr;
            ah[mt] = *(const bf16x8*)&sAh[row * 32 + ks * 8];
            al[mt] = *(const bf16x8*)&sAl[row * 32 + ks * 8];
            int col = wn * HM + mt * 16 + lr;
            bh[mt] = *(const bf16x8*)&sBh[col * 32 + ks * 8];
            bl[mt] = *(const bf16x8*)&sBl[col * 32 + ks * 8];
        }
#pragma unroll
        for (int mt = 0; mt < MT; ++mt)
#pragma unroll
            for (int nt = 0; nt < MT; ++nt) {
                acc[mt][nt] = __builtin_amdgcn_mfma_f32_16x16x32_bf16(
                    ah[mt], bh[nt], acc[mt][nt], 0, 0, 0);
                acc[mt][nt] = __builtin_amdgcn_mfma_f32_16x16x32_bf16(
                    ah[mt], bl[nt], acc[mt][nt], 0, 0, 0);
                acc[mt][nt] = __builtin_amdgcn_mfma_f32_16x16x32_bf16(
                    al[mt], bh[nt], acc[mt][nt], 0, 0, 0);
            }
        __syncthreads();
    }

    const int rq = lane >> 4, cq = lane & 15;
#pragma unroll
    for (int mt = 0; mt < MT; ++mt)
#pragma unroll
        for (int nt = 0; nt < MT; ++nt) {
            int gr0 = m0 + wm * HM + mt * 16 + rq * 4;
            int gc  = n0 + wn * HM + nt * 16 + cq;
            float vv[4];
            float bv = (MODE == 5) ? 0.f : bias[gc];
#pragma unroll
            for (int i = 0; i < 4; ++i) {
                float v = acc[mt][nt][i] + bv;
                if (ACT == 1) v = fmaxf(v, 0.f);
                vv[i] = v;
            }
            if (MODE == 0 || MODE == 5) {
#pragma unroll
                for (int i = 0; i < 4; ++i)
                    C[(long)(gr0 + i) * ldc + gc + z * zC] = vv[i];
            } else if (MODE == 2) {
#pragma unroll
                for (int i = 0; i < 4; ++i) {
                    long off = (long)(gr0 + i) * ldc + gc;
                    short h = f2bf(vv[i]);
                    Ch[off] = h;
                    Cl[off] = f2bf(vv[i] - bf2f(h));
                }
            } else {               // MODE 3
                if ((int)z == vtZ) {
                    // direct transposed V write: VT[bh][dk][s swizzled]
                    int b = gr0 >> 10, s0 = gr0 & (SEQ - 1);
                    int hh2 = gc >> 6, dk = gc & 63;
                    int swz = (((dk >> 1) & 3) << 3) | (((dk >> 3) & 1) << 5);
                    long base = (((long)(b * NHEAD + hh2)) * 64 + dk) * 1024
                              + (long)(((s0 & ~7) ^ swz) | (s0 & 7));
                    short4v hv, lv;
#pragma unroll
                    for (int i = 0; i < 4; ++i) {
                        short h = f2bf(vv[i]);
                        hv[i] = h;
                        lv[i] = f2bf(vv[i] - bf2f(h));
                    }
                    *(short4v*)&VTh[base] = hv;
                    *(short4v*)&VTl[base] = lv;
                } else {
                    float sc = ((int)z == scaledZ) ? 0.125f : 1.f;
#pragma unroll
                    for (int i = 0; i < 4; ++i) {
                        float v2 = vv[i] * sc;
                        int gr = gr0 + i;
                        int b = gr >> 10, s = gr & (SEQ - 1);
                        int hh2 = gc >> 6, dk = gc & 63;
                        int dks = dk ^ (((s >> 1) & 7) << 3);
                        long oidx = z * zC +
                            (((long)(b * NHEAD + hh2)) * SEQ + s) * 64 + dks;
                        short h = f2bf(v2);
                        Ch[oidx] = h;
                        Cl[oidx] = f2bf(v2 - bf2f(h));
                    }
                }
            }
        }
}

// ---------------- Qc combine: part0+part1+bias -> *0.125 -> MODE3 layout ----
__global__ __launch_bounds__(256) void qc_combine_kernel(
    const float* __restrict__ p0, const float* __restrict__ p1,
    const float* __restrict__ bias, short* __restrict__ Qh, short* __restrict__ Ql)
{
    long idx = (long)blockIdx.x * 256 + threadIdx.x;   // 262144 total
    int gr = (int)(idx >> 7);
    int gc4 = (int)(idx & 127) * 4;
    float4 a = *(const float4*)&p0[(long)gr * 512 + gc4];
    float4 b2 = *(const float4*)&p1[(long)gr * 512 + gc4];
    float4 bv = *(const float4*)&bias[gc4];
    float v[4] = {(a.x + b2.x + bv.x) * 0.125f, (a.y + b2.y + bv.y) * 0.125f,
                  (a.z + b2.z + bv.z) * 0.125f, (a.w + b2.w + bv.w) * 0.125f};
    int b = gr >> 10, s = gr & (SEQ - 1);
    int hh = gc4 >> 6, dk4 = gc4 & 63;
    int dks = dk4 ^ (((s >> 1) & 7) << 3);
    long o = (((long)(b * NHEAD + hh)) * SEQ + s) * 64 + dks;
    short4v hv, lv;
#pragma unroll
    for (int i = 0; i < 4; ++i) {
        short h = f2bf(v[i]);
        hv[i] = h;
        lv[i] = f2bf(v[i] - bf2f(h));
    }
    *(short4v*)&Qh[o] = hv;
    *(short4v*)&Ql[o] = lv;
}

// ---------------- fused attention: 32 q-rows, 2 waves, 2 blocks/CU ----------
template<bool CAUSAL>
__global__ __launch_bounds__(128) void attn_fused_kernel(
    const short* __restrict__ Qh, const short* __restrict__ Ql,
    const short* __restrict__ Kh, const short* __restrict__ Kl,
    const short* __restrict__ VTh, const short* __restrict__ VTl,
    float* __restrict__ attn, short* __restrict__ Oh, short* __restrict__ Ol)
{
    const int strip = blockIdx.x, bh = blockIdx.y;
    const int q0 = strip * 32;
    const int t = threadIdx.x, w = t >> 6, lane = t & 63;
    const int lr = lane & 15, ks = lane >> 4;
    const int rq = lane >> 4, cq = lane & 15;
    const int sxq = (lr >> 1) & 7;

    __shared__ short sKh[2][64*64], sKl[2][64*64];   // 32 KB
    __shared__ short sVh[2][64*64], sVl[2][64*64];   // 32 KB
    __shared__ short sPh[2][16*80], sPl[2][16*80];   // 10 KB

    const int diag  = strip >> 1;                     // tile containing the diagonal
    const int ktmax = CAUSAL ? diag + 1 : 16;

    // Q stage (32 rows) via sVh[0]/sVl[0]
    {
        const long qb = ((long)bh * SEQ + q0) * 128;
#pragma unroll
        for (int i2 = 0; i2 < 2; ++i2) {
            int L = i2 * 2048 + t * 16; int r = L >> 7, off = L & 127;
            gld16((const char*)Qh + qb + (long)r*128 + off, (char*)&sVh[0][0] + L);
            gld16((const char*)Ql + qb + (long)r*128 + off, (char*)&sVl[0][0] + L);
        }
    }
    __syncthreads();
    bf16x8 qa[2][2];
#pragma unroll
    for (int k0 = 0; k0 < 2; ++k0) {
        int o = (w*16 + lr) * 64 + ((k0*32 + ks*8) ^ (sxq << 3));
        qa[k0][0] = *(const bf16x8*)&sVh[0][o];
        qa[k0][1] = *(const bf16x8*)&sVl[0][o];
    }
    __syncthreads();

    auto stageK = [&](int buf, int kt) {
        const long kb = ((long)bh * SEQ + kt*64) * 128;
#pragma unroll
        for (int i2 = 0; i2 < 4; ++i2) {
            int L = i2*2048 + t*16; int r = L >> 7, off = L & 127;
            gld16((const char*)Kh + kb + (long)r*128 + off, (char*)&sKh[buf][0] + L);
            gld16((const char*)Kl + kb + (long)r*128 + off, (char*)&sKl[buf][0] + L);
        }
    };
    auto stageV = [&](int buf, int kt) {
        const long vb = ((long)bh * 64) * 2048 + (long)kt * 128;
#pragma unroll
        for (int i2 = 0; i2 < 4; ++i2) {
            int L = i2*2048 + t*16; int r = L >> 7, off = L & 127;
            gld16((const char*)VTh + vb + (long)r*2048 + off, (char*)&sVh[buf][0] + L);
            gld16((const char*)VTl + vb + (long)r*2048 + off, (char*)&sVl[buf][0] + L);
        }
    };
    auto scoresOf = [&](int buf, int kt, f32x4* sc) {
#pragma unroll
        for (int nt = 0; nt < 4; ++nt) sc[nt] = (f32x4){0.f, 0.f, 0.f, 0.f};
#pragma unroll
        for (int k0 = 0; k0 < 2; ++k0) {
            bf16x8 kh[4], kl[4];
#pragma unroll
            for (int nt = 0; nt < 4; ++nt) {
                int o = (nt*16 + lr) * 64 + ((k0*32 + ks*8) ^ (sxq << 3));
                kh[nt] = *(const bf16x8*)&sKh[buf][o];
                kl[nt] = *(const bf16x8*)&sKl[buf][o];
            }
#pragma unroll
            for (int nt = 0; nt < 4; ++nt) {
                sc[nt] = __builtin_amdgcn_mfma_f32_16x16x32_bf16(
                    qa[k0][0], kh[nt], sc[nt], 0, 0, 0);
                sc[nt] = __builtin_amdgcn_mfma_f32_16x16x32_bf16(
                    qa[k0][0], kl[nt], sc[nt], 0, 0, 0);
                sc[nt] = __builtin_amdgcn_mfma_f32_16x16x32_bf16(
                    qa[k0][1], kh[nt], sc[nt], 0, 0, 0);
            }
        }
        if (CAUSAL && kt == diag) {
            int row = q0 + w*16 + rq*4;
#pragma unroll
            for (int nt = 0; nt < 4; ++nt) {
                int col = kt*64 + nt*16 + cq;
#pragma unroll
                for (int i = 0; i < 4; ++i)
                    if (col > row + i) sc[nt][i] = -1e9f;
            }
        }
    };

    // ---- pass 1: online max + sum ----
    float m[4]   = {-3e38f, -3e38f, -3e38f, -3e38f};
    float sum[4] = {0.f, 0.f, 0.f, 0.f};
    int cur = 0;
    stageK(0, 0);
    __syncthreads();
    for (int kt = 0; kt < ktmax; ++kt) {
        if (kt + 1 < ktmax) stageK(cur ^ 1, kt + 1);
        f32x4 sc[4];
        scoresOf(cur, kt, sc);
#pragma unroll
        for (int i = 0; i < 4; ++i) {
            float tm = fmaxf(fmaxf(sc[0][i], sc[1][i]), fmaxf(sc[2][i], sc[3][i]));
#pragma unroll
            for (int d2 = 1; d2 <= 8; d2 <<= 1) tm = fmaxf(tm, __shfl_xor(tm, d2, 64));
            float mn = fmaxf(m[i], tm);
            float ps = __expf(sc[0][i] - mn) + __expf(sc[1][i] - mn)
                     + __expf(sc[2][i] - mn) + __expf(sc[3][i] - mn);
#pragma unroll
            for (int d2 = 1; d2 <= 8; d2 <<= 1) ps += __shfl_xor(ps, d2, 64);
            sum[i] = sum[i] * __expf(m[i] - mn) + ps;
            m[i] = mn;
        }
        __syncthreads();
        cur ^= 1;
    }
    float inv[4];
#pragma unroll
    for (int i = 0; i < 4; ++i) inv[i] = 1.f / sum[i];

    // ---- pass 2: recompute, probs out, PV ----
    f32x4 acco[4];
#pragma unroll
    for (int nt = 0; nt < 4; ++nt) acco[nt] = (f32x4){0.f, 0.f, 0.f, 0.f};

    cur = 0;
    stageK(0, 0); stageV(0, 0);
    __syncthreads();
    for (int kt = 0; kt < 16; ++kt) {
        if (kt >= ktmax) {                      // causal: p == 0
#pragma unroll
            for (int nt = 0; nt < 4; ++nt)
#pragma unroll
                for (int i = 0; i < 4; ++i)
                    attn[((long)bh << 20) + ((long)(q0 + w*16 + rq*4 + i) << 10)
                         + kt*64 + nt*16 + cq] = 0.f;
            continue;
        }
        if (kt + 1 < ktmax) { stageK(cur ^ 1, kt + 1); stageV(cur ^ 1, kt + 1); }
        f32x4 sc[4];
        scoresOf(cur, kt, sc);
#pragma unroll
        for (int nt = 0; nt < 4; ++nt)
#pragma unroll
            for (int i = 0; i < 4; ++i) {
                float p = __expf(sc[nt][i] - m[i]) * inv[i];
                attn[((long)bh << 20) + ((long)(q0 + w*16 + rq*4 + i) << 10)
                     + kt*64 + nt*16 + cq] = p;
                short ph = f2bf(p);
                sPh[w][(rq*4 + i)*80 + nt*16 + cq] = ph;
                sPl[w][(rq*4 + i)*80 + nt*16 + cq] = f2bf(p - bf2f(ph));
            }
#pragma unroll
        for (int k0 = 0; k0 < 2; ++k0) {
            bf16x8 pah = *(const bf16x8*)&sPh[w][lr*80 + k0*32 + ks*8];
            bf16x8 pal = *(const bf16x8*)&sPl[w][lr*80 + k0*32 + ks*8];
#pragma unroll
            for (int nt = 0; nt < 4; ++nt) {
                int dk = nt*16 + lr;
                int swz = (((dk >> 1) & 3) << 3) | (((dk >> 3) & 1) << 5);
                int koff = (k0*32 + ks*8) ^ swz;
                bf16x8 vh8 = *(const bf16x8*)&sVh[cur][dk*64 + koff];
                bf16x8 vl8 = *(const bf16x8*)&sVl[cur][dk*64 + koff];
                acco[nt] = __builtin_amdgcn_mfma_f32_16x16x32_bf16(
                    pah, vh8, acco[nt], 0, 0, 0);
                acco[nt] = __builtin_amdgcn_mfma_f32_16x16x32_bf16(
                    pah, vl8, acco[nt], 0, 0, 0);
                acco[nt] = __builtin_amdgcn_mfma_f32_16x16x32_bf16(
                    pal, vh8, acco[nt], 0, 0, 0);
            }
        }
        __syncthreads();
        cur ^= 1;
    }

    const int b = bh >> 3, hh_ = bh & 7;
#pragma unroll
    for (int nt = 0; nt < 4; ++nt)
#pragma unroll
        for (int i = 0; i < 4; ++i) {
            float v = acco[nt][i];
            long oidx = ((long)(b * SEQ + q0 + w*16 + rq*4 + i)) * D_MODEL
                      + hh_*64 + nt*16 + cq;
            short h2 = f2bf(v);
            Oh[oidx] = h2;
            Ol[oidx] = f2bf(v - bf2f(h2));
        }
}

// ---------------- residual + NS partial slabs + bias + LayerNorm + hi/lo ----
template<int NS>
__global__ __launch_bounds__(256) void add_ln_kernel(
    const float* __restrict__ xin, const float* __restrict__ part, long PS,
    const float* __restrict__ bias,
    const float* __restrict__ g, const float* __restrict__ bb,
    float* __restrict__ xout, short* __restrict__ xh, short* __restrict__ xl)
{
    long row = blockIdx.x;
    const float* xr = xin + row * D_MODEL;
    float*       xo = xout+ row * D_MODEL;
    short*       hh = xh  + row * D_MODEL;
    short*       ll = xl  + row * D_MODEL;
    int t = threadIdx.x;

    float a0 = xr[t]       + bias[t];
    float a1 = xr[t + 256] + bias[t + 256];
#pragma unroll
    for (int s2 = 0; s2 < NS; ++s2) {
        a0 += part[s2 * PS + row * D_MODEL + t];
        a1 += part[s2 * PS + row * D_MODEL + t + 256];
    }

    float s = a0 + a1;
#pragma unroll
    for (int m = 32; m; m >>= 1) s += __shfl_xor(s, m, 64);
    __shared__ float red1[4];
    __shared__ float red2[4];
    int w = t >> 6, lane = t & 63;
    if (lane == 0) red1[w] = s;
    __syncthreads();
    float mean = (red1[0] + red1[1] + red1[2] + red1[3]) * (1.f / 512.f);

    float d0 = a0 - mean, d1 = a1 - mean;
    float q = d0 * d0 + d1 * d1;
#pragma unroll
    for (int m = 32; m; m >>= 1) q += __shfl_xor(q, m, 64);
    if (lane == 0) red2[w] = q;
    __syncthreads();
    float var  = (red2[0] + red2[1] + red2[2] + red2[3]) * (1.f / 512.f);
    float rstd = rsqrtf(var + 1e-5f);

    float r0 = d0 * rstd * g[t]       + bb[t];
    float r1 = d1 * rstd * g[t + 256] + bb[t + 256];
    xo[t] = r0; xo[t + 256] = r1;
    short h0 = f2bf(r0); hh[t] = h0;       ll[t] = f2bf(r0 - bf2f(h0));
    short h1 = f2bf(r1); hh[t + 256] = h1; ll[t + 256] = f2bf(r1 - bf2f(h1));
}

// ---------------------------------------------------------------------------
extern "C" void kernel_launch(void* const* d_in, const int* in_sizes, int n_in,
                              void* d_out, int out_size, void* d_ws, size_t ws_size,
                              hipStream_t stream)
{
    const int*   tokens = (const int*)  d_in[0];
    const float* enc    = (const float*)d_in[1];
    const float* emb    = (const float*)d_in[3];
    const float* Wqkvo  = (const float*)d_in[4];   // [L,2,4,D,D]
    const float* bqkvo  = (const float*)d_in[5];   // [L,2,4,D]
    const float* W1     = (const float*)d_in[6];   // [L,D,DFF]
    const float* b1     = (const float*)d_in[7];
    const float* W2     = (const float*)d_in[8];   // [L,DFF,D]
    const float* b2     = (const float*)d_in[9];
    const float* lng    = (const float*)d_in[10];  // [L,3,D]
    const float* lnb    = (const float*)d_in[11];
    const float* Wout   = (const float*)d_in[12];  // [D,V]
    const float* bout   = (const float*)d_in[13];

    float* out    = (float*)d_out;
    float* selfA  = out + 65536000L;
    float* crossA = selfA + 67108864L;

    // workspace carve (~112 MB)
    char* p = (char*)d_ws;
    auto carve = [&](size_t bytes) { char* r = p; p += (bytes + 255) & ~255UL; return r; };
    float* x      = (float*)carve(1048576L * 4);
    short* xh     = (short*)carve(1048576L * 2);
    short* xl     = (short*)carve(1048576L * 2);
    short* ench   = (short*)carve(1048576L * 2);
    short* encl   = (short*)carve(1048576L * 2);
    short* qh     = (short*)carve(2097152L * 2);   // head-major Q|K hi
    short* ql     = (short*)carve(2097152L * 2);   // head-major Q|K lo
    short* vth    = (short*)carve(1048576L * 2);   // transposed V hi
    short* vtl    = (short*)carve(1048576L * 2);
    short* oh     = (short*)carve(1048576L * 2);
    short* ol     = (short*)carve(1048576L * 2);
    short* t1h    = (short*)carve(4194304L * 2);   // FFN1 out hi
    short* t1l    = (short*)carve(4194304L * 2);
    float* part   = (float*)carve(4L * 1048576L * 4);  // 4 K-split slabs
    short* WTLh   = (short*)carve(4194304L * 2);   // per-layer weights T hi
    short* WTLl   = (short*)carve(4194304L * 2);
    short* WTh    = (short*)carve(8192000L * 2);   // vocab chunk T hi
    short* WTl    = (short*)carve(8192000L * 2);

    const long PW = 262144L;    // 512*512
    const long HS = 1048576L;   // per attention operand slab
    const long PSLAB = 1048576L;

    embed_pe_kernel<<<4096, 256, 0, stream>>>(tokens, emb, x, xh, xl);
    cvt_kernel<<<1024, 256, 0, stream>>>(enc, ench, encl);

    for (int l = 0; l < NLAYER; ++l) {
        const float* bl = bqkvo + (long)l * 4096L;
        const float* bc = bl + 2048;
        const float* g  = lng + (long)l * 3 * 512;
        const float* bb = lnb + (long)l * 3 * 512;

        wtrans_layer_kernel<<<1024, 256, 0, stream>>>(Wqkvo, W1, W2, l, WTLh, WTLl);

        // ---- self-attention ----
        gemm_mfma_kernel<64,0,3><<<dim3(8, 32, 3), 256, 0, stream>>>(
            xh, xl, WTLh, WTLl, bl, nullptr, qh, ql, vth, vtl,
            512, 512, 512, 0, PW, 512, HS, 0, /*scaledZ=*/0, /*vtZ=*/2);
        attn_fused_kernel<true><<<dim3(32, 16), 128, 0, stream>>>(
            qh, ql, qh + HS, ql + HS, vth, vtl,
            selfA + (long)l * 16777216L, oh, ol);
        gemm_mfma_kernel<64,0,5><<<dim3(8, 32, 2), 256, 0, stream>>>(
            oh, ol, WTLh + 3*PW, WTLl + 3*PW, nullptr, part, nullptr, nullptr,
            nullptr, nullptr, 256, 512, 512, 512, 0, 0, PSLAB, 256, -1, -1);
        add_ln_kernel<2><<<MROWS, 256, 0, stream>>>(
            x, part, PSLAB, bl + 3*512, g, bb, x, xh, xl);

        // ---- cross-attention ----
        gemm_mfma_kernel<64,0,5><<<dim3(8, 32, 2), 256, 0, stream>>>(
            xh, xl, WTLh + 4*PW, WTLl + 4*PW, nullptr, part, nullptr, nullptr,
            nullptr, nullptr, 256, 512, 512, 512, 0, 0, PSLAB, 256, -1, -1);
        qc_combine_kernel<<<1024, 256, 0, stream>>>(part, part + PSLAB, bc, qh, ql);
        gemm_mfma_kernel<64,0,3><<<dim3(8, 32, 2), 256, 0, stream>>>(
            ench, encl, WTLh + 5*PW, WTLl + 5*PW, bc + 512, nullptr,
            qh + HS, ql + HS, vth, vtl,
            512, 512, 512, 0, PW, 512, HS, 0, /*scaledZ=*/-1, /*vtZ=*/1);
        attn_fused_kernel<false><<<dim3(32, 16), 128, 0, stream>>>(
            qh, ql, qh + HS, ql + HS, vth, vtl,
            crossA + (long)l * 16777216L, oh, ol);
        gemm_mfma_kernel<64,0,5><<<dim3(8, 32, 2), 256, 0, stream>>>(
            oh, ol, WTLh + 7*PW, WTLl + 7*PW, nullptr, part, nullptr, nullptr,
            nullptr, nullptr, 256, 512, 512, 512, 0, 0, PSLAB, 256, -1, -1);
        add_ln_kernel<2><<<MROWS, 256, 0, stream>>>(
            x, part, PSLAB, bc + 3*512, g + 512, bb + 512, x, xh, xl);

        // ---- FFN ----
        gemm_mfma_kernel<64,1,2><<<dim3(32, 32, 1), 256, 0, stream>>>(
            xh, xl, WTLh + 2097152L, WTLl + 2097152L, b1 + (long)l * 2048,
            nullptr, t1h, t1l, nullptr, nullptr,
            512, 512, 512, 2048, 0, 0, 0, 0, -1, -1);
        gemm_mfma_kernel<64,0,5><<<dim3(8, 32, 4), 256, 0, stream>>>(
            t1h, t1l, WTLh + 3145728L, WTLl + 3145728L, nullptr, part,
            nullptr, nullptr, nullptr, nullptr,
            512, 2048, 2048, 512, 0, 0, PSLAB, 512, -1, -1);
        add_ln_kernel<4><<<MROWS, 256, 0, stream>>>(
            x, part, PSLAB, b2 + (long)l * 512, g + 1024, bb + 1024, x, xh, xl);
    }

    // ---- final vocab projection, two 16000-wide chunks ----
    for (int c = 0; c < 2; ++c) {
        wtrans_kernel<<<dim3(250, 8, 1), 256, 0, stream>>>(
            Wout + c * 16000, WTh, WTl, 512, VOCAB);
        gemm_mfma_kernel<128,0,0><<<dim3(125, 16, 1), 256, 0, stream>>>(
            xh, xl, WTh, WTl, bout + c * 16000, out + c * 16000,
            nullptr, nullptr, nullptr, nullptr,
            512, 512, 512, VOCAB, 0, 0, 0, 0, -1, -1);
    }
}